// Round 2
// baseline (777.634 us; speedup 1.0000x reference)
//
#include <hip/hip_runtime.h>
#include <hip/hip_bf16.h>
#include <stdint.h>

#define BB 2
#define SB 2048
#define DD 512
#define HH 4
#define VV 32000

typedef __attribute__((ext_vector_type(4))) float f32x4;
typedef __attribute__((ext_vector_type(8))) short bf16x8;
typedef __attribute__((ext_vector_type(4))) unsigned short us4;

__device__ __forceinline__ unsigned short f2bf(float f) {
    unsigned u = __float_as_uint(f);
    u += 0x7fffu + ((u >> 16) & 1u);
    return (unsigned short)(u >> 16);
}
__device__ __forceinline__ float bf2f(unsigned short b) {
    return __uint_as_float(((unsigned)b) << 16);
}

__device__ __forceinline__ __attribute__((address_space(3))) unsigned int*
as_lds(void* p) {
    return (__attribute__((address_space(3))) unsigned int*)(unsigned)(uintptr_t)p;
}
__device__ __forceinline__ const __attribute__((address_space(1))) unsigned int*
as_gbl(const void* p) {
    return (const __attribute__((address_space(1))) unsigned int*)(uintptr_t)p;
}

// ---------------- f32 -> bf16 convert (vectorized, grid-stride) ----------------
__global__ void k_cvt_bf16(const float* __restrict__ src, unsigned short* __restrict__ dst, int n) {
    int idx = (blockIdx.x * blockDim.x + threadIdx.x) * 4;
    int stride = gridDim.x * blockDim.x * 4;
    for (int i = idx; i < n; i += stride) {
        float4 v = *(const float4*)(src + i);
        us4 o;
        o.x = f2bf(v.x); o.y = f2bf(v.y); o.z = f2bf(v.z); o.w = f2bf(v.w);
        *(us4*)(dst + i) = o;
    }
}

// ---------------- embedding gather + bf16 cast ----------------
__global__ void k_embed(const int* __restrict__ ids, const float* __restrict__ tbl,
                        unsigned short* __restrict__ emb) {
    int row = blockIdx.x;                 // 0..B*S-1
    int id = ids[row];
    if (id < 0) id = 0;
    if (id >= VV) id = VV - 1;            // safety clamp
    const float* s = tbl + (size_t)id * DD;
    unsigned short* d = emb + (size_t)row * DD;
    int t = threadIdx.x;                  // 256 threads
    d[t]       = f2bf(s[t]);
    d[t + 256] = f2bf(s[t + 256]);
}

// ---------------- fused windowed attention (canonical fragments only) ----------------
// grid: (qt=32, b=2, h=4), block 256 (4 waves, 16 q-rows each).
// No running max needed: |scores| <= ~1e-2 so exp() is safe unnormalized.
__launch_bounds__(256, 1)
__global__ void k_attn(const unsigned short* __restrict__ emb,   // [B*S, D] bf16 bits
                       const unsigned char* __restrict__ pad,    // [B, S] (all-false here)
                       const float* __restrict__ sfs,            // [H]
                       const float* __restrict__ als,            // [H]
                       unsigned short* __restrict__ concat)      // [B*S, H*D] bf16 bits
{
    const int qt = blockIdx.x, b = blockIdx.y, h = blockIdx.z;
    const int tid = threadIdx.x;
    const int lane = tid & 63, wv = tid >> 6;
    const int l15 = lane & 15, g = lane >> 4;
    const int qbase = qt * 64;
    const int q0 = qbase + wv * 16;
    const int myq = q0 + l15;

    const float alpha = als[h];
    const float sf = sfs[h];
    const int win = (h == 1) ? 128 : (h == 2) ? 512 : (1 << 30);

    __shared__ __align__(16) unsigned short VT[DD * 32];       // VT[d][k] transposed V tile
    __shared__ __align__(16) unsigned short Pl[4][16 * 32];    // per-wave P[q][k]

    const unsigned short* ebase = emb + (size_t)b * SB * DD;

    // Hoist Q fragments (B-operand of scores^T): lane holds Q[myq][dsl*32 + 8g .. +8]
    bf16x8 qf[16];
    {
        const unsigned short* qrow = ebase + (size_t)myq * DD + 8 * g;
#pragma unroll
        for (int dsl = 0; dsl < 16; ++dsl)
            qf[dsl] = *(const bf16x8*)(qrow + dsl * 32);
    }

    f32x4 zero4 = {0.f, 0.f, 0.f, 0.f};
    f32x4 acc[32];                 // acc[dt] = ctx^T tile: [d-within-16][q]
#pragma unroll
    for (int i = 0; i < 32; ++i) acc[i] = zero4;
    float lsum = 0.f;

    int klo = qbase - win;
    if (klo < 0) klo = 0;
    klo &= ~31;
    const int khi = qbase + 64;

    for (int kb = klo; kb < khi; kb += 32) {
        __syncthreads();
        // ---- stage V^T tile (block-wide): VT[d][k] = V[kb+k][d] ----
#pragma unroll
        for (int it = 0; it < 8; ++it) {
            int flat = it * 256 + tid;         // 2048 chunks of 8 dims
            int k = flat & 31;
            int d0 = (flat >> 5) * 8;
            bf16x8 v = *(const bf16x8*)(ebase + (size_t)(kb + k) * DD + d0);
#pragma unroll
            for (int j = 0; j < 8; ++j)
                VT[(d0 + j) * 32 + k] = (unsigned short)v[j];
        }
        __syncthreads();

        // per-wave skip of fully-masked tiles (wave-uniform branch)
        if (kb <= q0 + 15 && kb + 31 >= q0 - win) {
            // scores^T = K * Q^T  (two key groups of 16)
            f32x4 c0 = zero4, c1 = zero4;
            const unsigned short* k0p = ebase + (size_t)(kb + l15) * DD + 8 * g;
#pragma unroll
            for (int dsl = 0; dsl < 16; ++dsl) {
                bf16x8 kf0 = *(const bf16x8*)(k0p + dsl * 32);
                bf16x8 kf1 = *(const bf16x8*)(k0p + 16 * DD + dsl * 32);
                c0 = __builtin_amdgcn_mfma_f32_16x16x32_bf16(kf0, qf[dsl], c0, 0, 0, 0);
                c1 = __builtin_amdgcn_mfma_f32_16x16x32_bf16(kf1, qf[dsl], c1, 0, 0, 0);
            }

            // pad bits for this 32-key tile via ballot (wave-uniform mask)
            unsigned int padm;
            {
                int kk = kb + (lane & 31);
                bool pp = (lane < 32) && (pad[(size_t)b * SB + kk] != 0);
                padm = (unsigned int)__ballot(pp);
            }

            const float rs = 0.04419417382415922f;  // 1/sqrt(512)
            unsigned short pbits[8];
            float ls = 0.f;
#pragma unroll
            for (int r = 0; r < 4; ++r) {
                {
                    int k = kb + 4 * g + r;
                    int dist = myq - k;
                    float s = c0[r] * rs / (1.f + alpha * (float)dist);
                    s = (dist == 0) ? s * sf : s;
                    bool ok = (dist >= 0) && (dist <= win) &&
                              ((dist == 0) || !((padm >> (4 * g + r)) & 1));
                    float p = ok ? __expf(s) : 0.f;
                    unsigned short pb = f2bf(p);
                    pbits[r] = pb;
                    ls += bf2f(pb);                  // denom matches bf16 numerator
                }
                {
                    int k = kb + 16 + 4 * g + r;
                    int dist = myq - k;
                    float s = c1[r] * rs / (1.f + alpha * (float)dist);
                    s = (dist == 0) ? s * sf : s;
                    bool ok = (dist >= 0) && (dist <= win) &&
                              ((dist == 0) || !((padm >> (16 + 4 * g + r)) & 1));
                    float p = ok ? __expf(s) : 0.f;
                    unsigned short pb = f2bf(p);
                    pbits[4 + r] = pb;
                    ls += bf2f(pb);
                }
            }
            lsum += ls;

            // ---- round-trip P through wave-private LDS to canonical B-fragment ----
            // lane holds P[q=l15][keys 4g+r] (c0) and [16+4g+r] (c1): contiguous 4-packs.
            {
                us4 lo, hi;
                lo.x = pbits[0]; lo.y = pbits[1]; lo.z = pbits[2]; lo.w = pbits[3];
                hi.x = pbits[4]; hi.y = pbits[5]; hi.z = pbits[6]; hi.w = pbits[7];
                *(us4*)&Pl[wv][l15 * 32 + 4 * g]      = lo;
                *(us4*)&Pl[wv][l15 * 32 + 16 + 4 * g] = hi;
            }
            // canonical B-fragment of P^T: B[k=8g+j][col=q=l15]
            bf16x8 ptf = *(const bf16x8*)&Pl[wv][l15 * 32 + 8 * g];

            // PV: ctx^T[d][q] = sum_k V^T[d][k] * P^T[k][q]
#pragma unroll
            for (int dt = 0; dt < 32; ++dt) {
                bf16x8 vtf = *(const bf16x8*)&VT[(dt * 16 + l15) * 32 + 8 * g];
                acc[dt] = __builtin_amdgcn_mfma_f32_16x16x32_bf16(vtf, ptf, acc[dt], 0, 0, 0);
            }
        }
    }

    // finalize: reduce denom across the 4 lane-groups (lanes sharing l15)
    lsum += __shfl_xor(lsum, 16, 64);
    lsum += __shfl_xor(lsum, 32, 64);
    float inv = 1.f / lsum;        // denominator for query q0 + l15

    // acc[dt][r] = ctx[q0+l15][dt*16 + 4g + r]
    unsigned short* cb = concat + (size_t)(b * SB + q0 + l15) * (HH * DD) + (size_t)h * DD;
#pragma unroll
    for (int dt = 0; dt < 32; ++dt) {
        us4 o;
        o.x = f2bf(acc[dt][0] * inv);
        o.y = f2bf(acc[dt][1] * inv);
        o.z = f2bf(acc[dt][2] * inv);
        o.w = f2bf(acc[dt][3] * inv);
        *(us4*)(cb + dt * 16 + 4 * g) = o;
    }
}

// ---------------- m97-style bf16 GEMM, B^T input, 128x128 tile, BK=32 ----------------
// C[m,n] = sum_k A[m,k]*Bt[n,k] + bias[n];  OUTF32: f32 out else bf16 out.
template <int OUTF32>
__launch_bounds__(256, 2)
__global__ void k_gemm_bt(const unsigned short* __restrict__ A,
                          const unsigned short* __restrict__ Bt,
                          const float* __restrict__ bias,
                          void* __restrict__ Cout,
                          int M, int N, int K)
{
    const int nMt = M >> 7;
    const int nwg = gridDim.x;
    int bid = blockIdx.x;
    // bijective XCD swizzle (m204): contiguous tile chunks per XCD, m-fastest
    int q = nwg >> 3, r = nwg & 7;
    int x = bid & 7, o = bid >> 3;
    int wg = (x < r ? x * (q + 1) : r * (q + 1) + (x - r) * q) + o;
    const int mt = wg % nMt, nt = wg / nMt;

    __shared__ __align__(16) unsigned short Al[128 * 32];
    __shared__ __align__(16) unsigned short Bl[128 * 32];

    const int tid = threadIdx.x;
    const int lane = tid & 63;
    const int wv = tid >> 6;
    const int wm = (wv >> 1) * 64, wn = (wv & 1) * 64;
    const int l15 = lane & 15, g = lane >> 4;

    f32x4 zero4 = {0.f, 0.f, 0.f, 0.f};
    f32x4 acc[4][4];
#pragma unroll
    for (int i = 0; i < 4; ++i)
#pragma unroll
        for (int j = 0; j < 4; ++j) acc[i][j] = zero4;

    const unsigned short* Ab = A + (size_t)mt * 128 * K;
    const unsigned short* Bb = Bt + (size_t)nt * 128 * K;

    for (int k0 = 0; k0 < K; k0 += 32) {
        __syncthreads();
#pragma unroll
        for (int s = 0; s < 2; ++s) {
            int e = (s * 256 + tid) * 8;       // elem in 128x32 tile
            int row = e >> 5, col = e & 31;
            __builtin_amdgcn_global_load_lds(as_gbl(Ab + (size_t)row * K + k0 + col),
                                             as_lds(Al + e), 16, 0, 0);
            __builtin_amdgcn_global_load_lds(as_gbl(Bb + (size_t)row * K + k0 + col),
                                             as_lds(Bl + e), 16, 0, 0);
        }
        asm volatile("s_waitcnt vmcnt(0)" ::: "memory");
        __syncthreads();

        bf16x8 af[4], bfr[4];
#pragma unroll
        for (int i = 0; i < 4; ++i) {
            af[i]  = *(const bf16x8*)(Al + (wm + i * 16 + l15) * 32 + 8 * g);
            bfr[i] = *(const bf16x8*)(Bl + (wn + i * 16 + l15) * 32 + 8 * g);
        }
#pragma unroll
        for (int i = 0; i < 4; ++i)
#pragma unroll
            for (int j = 0; j < 4; ++j)
                acc[i][j] = __builtin_amdgcn_mfma_f32_16x16x32_bf16(af[i], bfr[j], acc[i][j], 0, 0, 0);
    }

#pragma unroll
    for (int i = 0; i < 4; ++i) {
        int rowb = mt * 128 + wm + i * 16 + g * 4;
#pragma unroll
        for (int j = 0; j < 4; ++j) {
            int col = nt * 128 + wn + j * 16 + l15;
            float bv = bias[col];
            if (OUTF32) {
                float* C = (float*)Cout;
#pragma unroll
                for (int rr = 0; rr < 4; ++rr)
                    C[(size_t)(rowb + rr) * N + col] = acc[i][j][rr] + bv;
            } else {
                unsigned short* C = (unsigned short*)Cout;
#pragma unroll
                for (int rr = 0; rr < 4; ++rr)
                    C[(size_t)(rowb + rr) * N + col] = f2bf(acc[i][j][rr] + bv);
            }
        }
    }
}

extern "C" void kernel_launch(void* const* d_in, const int* in_sizes, int n_in,
                              void* d_out, int out_size, void* d_ws, size_t ws_size,
                              hipStream_t stream)
{
    const int*           ids = (const int*)d_in[0];
    const unsigned char* pad = (const unsigned char*)d_in[1];
    const float*         tbl = (const float*)d_in[2];
    const float*         sfs = (const float*)d_in[3];
    const float*         als = (const float*)d_in[4];
    const float*         fw  = (const float*)d_in[5];
    const float*         fb  = (const float*)d_in[6];
    const float*         ow  = (const float*)d_in[7];
    const float*         ob  = (const float*)d_in[8];
    float* logits = (float*)d_out;

    char* ws = (char*)d_ws;
    unsigned short* outw_bf = (unsigned short*)(ws);              // 32,768,000 B
    unsigned short* fusw_bf = (unsigned short*)(ws + 32768000);   //  2,097,152 B
    unsigned short* emb_bf  = (unsigned short*)(ws + 34865152);   //  4,194,304 B
    unsigned short* concat  = (unsigned short*)(ws + 39059456);   // 16,777,216 B
    unsigned short* fused   = (unsigned short*)(ws + 55836672);   //  4,194,304 B
    // total 60,030,976 B of d_ws used

    k_cvt_bf16<<<2048, 256, 0, stream>>>(ow, outw_bf, VV * DD);
    k_cvt_bf16<<<512, 256, 0, stream>>>(fw, fusw_bf, DD * HH * DD);
    k_embed<<<BB * SB, 256, 0, stream>>>(ids, tbl, emb_bf);

    dim3 ag(32, BB, HH);
    k_attn<<<ag, 256, 0, stream>>>(emb_bf, pad, sfs, als, concat);

    k_gemm_bt<0><<<32 * 4, 256, 0, stream>>>(concat, fusw_bf, fb, fused, BB * SB, DD, HH * DD);
    k_gemm_bt<1><<<32 * 250, 256, 0, stream>>>(fused, outw_bf, ob, logits, BB * SB, VV, DD);
}

// Round 3
// 394.758 us; speedup vs baseline: 1.9699x; 1.9699x over previous
//
#include <hip/hip_runtime.h>
#include <hip/hip_bf16.h>
#include <stdint.h>

#define BB 2
#define SB 2048
#define DD 512
#define HH 4
#define VV 32000

typedef __attribute__((ext_vector_type(4))) float f32x4;
typedef __attribute__((ext_vector_type(8))) short bf16x8;
typedef __attribute__((ext_vector_type(4))) unsigned short us4;

__device__ __forceinline__ unsigned short f2bf(float f) {
    unsigned u = __float_as_uint(f);
    u += 0x7fffu + ((u >> 16) & 1u);
    return (unsigned short)(u >> 16);
}

__device__ __forceinline__ __attribute__((address_space(3))) unsigned int*
as_lds(void* p) {
    return (__attribute__((address_space(3))) unsigned int*)(unsigned)(uintptr_t)p;
}
__device__ __forceinline__ const __attribute__((address_space(1))) unsigned int*
as_gbl(const void* p) {
    return (const __attribute__((address_space(1))) unsigned int*)(uintptr_t)p;
}

// ---------------- f32 -> bf16 convert ----------------
__global__ void k_cvt_bf16(const float* __restrict__ src, unsigned short* __restrict__ dst, int n) {
    int idx = (blockIdx.x * blockDim.x + threadIdx.x) * 4;
    int stride = gridDim.x * blockDim.x * 4;
    for (int i = idx; i < n; i += stride) {
        float4 v = *(const float4*)(src + i);
        us4 o;
        o.x = f2bf(v.x); o.y = f2bf(v.y); o.z = f2bf(v.z); o.w = f2bf(v.w);
        *(us4*)(dst + i) = o;
    }
}

// ---------------- embedding gather + bf16 cast ----------------
__global__ void k_embed(const int* __restrict__ ids, const float* __restrict__ tbl,
                        unsigned short* __restrict__ emb) {
    int row = blockIdx.x;
    int id = ids[row];
    if (id < 0) id = 0;
    if (id >= VV) id = VV - 1;
    const float* s = tbl + (size_t)id * DD;
    unsigned short* d = emb + (size_t)row * DD;
    int t = threadIdx.x;
    d[t]       = f2bf(s[t]);
    d[t + 256] = f2bf(s[t + 256]);
}

// ---------------- decay table + lsum zero ----------------
__global__ void k_dtab_lsum(const float* __restrict__ als,
                            float* __restrict__ dtab, float* __restrict__ lsum) {
    int i = blockIdx.x * 256 + threadIdx.x;          // 96*256 = 24576
    if (i < HH * SB) {
        int h = i >> 11, d = i & (SB - 1);
        dtab[i] = 0.04419417382415922f / (1.f + als[h] * (float)d);
    } else {
        lsum[i - HH * SB] = 0.f;                     // 16384 entries
    }
}

// ---------------- emb transpose: embT[b][d][s] ----------------
__global__ void k_embT(const unsigned short* __restrict__ emb, unsigned short* __restrict__ embT) {
    const int d0 = blockIdx.x * 64, s0 = blockIdx.y * 64, b = blockIdx.z;
    __shared__ unsigned short TT[64][72];
    const int t = threadIdx.x;
    {
        int s = t >> 2, c16 = (t & 3) * 16;
        const unsigned short* src = emb + ((size_t)(b * SB + s0 + s)) * DD + d0 + c16;
        bf16x8 v0 = *(const bf16x8*)src;
        bf16x8 v1 = *(const bf16x8*)(src + 8);
#pragma unroll
        for (int j = 0; j < 8; ++j) {
            TT[c16 + j][s]     = (unsigned short)v0[j];
            TT[c16 + 8 + j][s] = (unsigned short)v1[j];
        }
    }
    __syncthreads();
    {
        int d = t >> 2, sc = (t & 3) * 16;
        bf16x8 o0, o1;
#pragma unroll
        for (int j = 0; j < 8; ++j) {
            o0[j] = (short)TT[d][sc + j];
            o1[j] = (short)TT[d][sc + 8 + j];
        }
        unsigned short* dst = embT + ((size_t)(b * DD + d0 + d)) * SB + s0 + sc;
        *(bf16x8*)dst = o0;
        *(bf16x8*)(dst + 8) = o1;
    }
}

// ---------------- phase 2: shared base QK^T -> per-head P tiles + row sums ----------------
// grid (kt=32, qt=32, b=2); block 256 = 4 waves; wave w owns q-strip w*16.
__launch_bounds__(256, 2)
__global__ void k_base(const unsigned short* __restrict__ emb,
                       const unsigned char* __restrict__ pad,
                       const float* __restrict__ sfs,
                       const float* __restrict__ dtab,
                       unsigned short* __restrict__ P,      // [4][2][2048][2048]
                       float* __restrict__ lsum)            // [4][2][2048]
{
    const int kt = blockIdx.x, qt = blockIdx.y, b = blockIdx.z;
    if (kt > qt + 1) return;
    const int tid = threadIdx.x, lane = tid & 63, wv = tid >> 6;
    const int l15 = lane & 15, g = lane >> 4;

    if (kt == qt + 1) {
        // fully-masked adjacent tile: write zeros for all heads (phase 3 reads it)
        int row = tid >> 2, cb = (tid & 3) * 16;
        int4 z = {0, 0, 0, 0};
#pragma unroll
        for (int h = 0; h < 4; ++h) {
            unsigned short* Ph = P + (((size_t)(h * 2 + b)) * SB + qt * 64 + row) * SB + kt * 64 + cb;
            *(int4*)Ph = z;
            *(int4*)(Ph + 8) = z;
        }
        return;
    }

    __shared__ __align__(16) unsigned short Ql[64 * 128];
    __shared__ __align__(16) unsigned short Kl[64 * 128];

    const int q = qt * 64 + wv * 16 + l15;

    f32x4 zero4 = {0.f, 0.f, 0.f, 0.f};
    f32x4 cc[4];
#pragma unroll
    for (int c = 0; c < 4; ++c) cc[c] = zero4;

    for (int dc = 0; dc < 4; ++dc) {
        const int d0 = dc * 128;
        __syncthreads();
#pragma unroll
        for (int i = 0; i < 4; ++i) {
            int flat = (i * 256 + tid) * 8;        // elem in [64][128]
            int row = flat >> 7;
            int ch  = (flat >> 3) & 15;
            int scol = ((ch ^ (row & 15)) << 3);   // pre-swizzled source column
            __builtin_amdgcn_global_load_lds(
                as_gbl(emb + ((size_t)(b * SB + qt * 64 + row)) * DD + d0 + scol),
                as_lds(Ql + flat), 16, 0, 0);
            __builtin_amdgcn_global_load_lds(
                as_gbl(emb + ((size_t)(b * SB + kt * 64 + row)) * DD + d0 + scol),
                as_lds(Kl + flat), 16, 0, 0);
        }
        asm volatile("s_waitcnt vmcnt(0)" ::: "memory");
        __syncthreads();

#pragma unroll
        for (int dsl = 0; dsl < 4; ++dsl) {
            int chr = (dsl * 4 + g);
            bf16x8 qf = *(const bf16x8*)(Ql + (wv * 16 + l15) * 128 + ((chr ^ l15) << 3));
#pragma unroll
            for (int c = 0; c < 4; ++c) {
                bf16x8 kf = *(const bf16x8*)(Kl + (c * 16 + l15) * 128 + ((chr ^ l15) << 3));
                cc[c] = __builtin_amdgcn_mfma_f32_16x16x32_bf16(kf, qf, cc[c], 0, 0, 0);
            }
        }
    }

    // pad mask for the 64 keys of this tile
    unsigned long long padm = __ballot(pad[(size_t)b * SB + kt * 64 + lane] != 0);

    const int wins[4] = {1 << 30, 128, 512, 1 << 30};
#pragma unroll
    for (int h = 0; h < 4; ++h) {
        const int win = wins[h];
        if (kt * 64 + win + 192 < qt * 64) continue;    // matches phase-3 read range
        const float sf = sfs[h];
        const float* dth = dtab + h * SB;
        float rsum = 0.f;
        unsigned short pb[4][4];
#pragma unroll
        for (int c = 0; c < 4; ++c) {
#pragma unroll
            for (int r = 0; r < 4; ++r) {
                int kk = kt * 64 + c * 16 + 4 * g + r;
                int dist = q - kk;
                float p = 0.f;
                if (dist >= 0 && dist <= win &&
                    ((dist == 0) || !((padm >> (c * 16 + 4 * g + r)) & 1ull))) {
                    float s = cc[c][r] * dth[dist];
                    if (dist == 0) s *= sf;
                    p = __expf(s);
                }
                rsum += p;
                pb[c][r] = f2bf(p);
            }
        }
        unsigned short* Ph = P + (((size_t)(h * 2 + b)) * SB + q) * SB + kt * 64;
#pragma unroll
        for (int c = 0; c < 4; ++c) {
            us4 o;
            o.x = pb[c][0]; o.y = pb[c][1]; o.z = pb[c][2]; o.w = pb[c][3];
            *(us4*)(Ph + c * 16 + 4 * g) = o;
        }
        rsum += __shfl_xor(rsum, 16, 64);
        rsum += __shfl_xor(rsum, 32, 64);
        if (lane < 16)
            atomicAdd(&lsum[((size_t)(h * 2 + b)) * SB + q], rsum);
    }
}

// ---------------- phase 3: ctx = P * V^T (m97 GEMM), normalize, write concat ----------------
// grid (64, b=2, h=4); tile 128q x 128d; K-loop bounded by window.
__launch_bounds__(256, 2)
__global__ void k_pv(const unsigned short* __restrict__ P,
                     const unsigned short* __restrict__ embT,
                     const float* __restrict__ lsum,
                     unsigned short* __restrict__ concat)
{
    const int t64 = blockIdx.x, b = blockIdx.y, h = blockIdx.z;
    const int mt = t64 >> 2, nt = t64 & 3;
    const int Q0 = mt * 128;
    const int win = (h == 1) ? 128 : (h == 2) ? 512 : (1 << 30);
    int klo = Q0 - win - 64; if (klo < 0) klo = 0; klo &= ~63;
    const int khi = Q0 + 128;

    __shared__ __align__(16) unsigned short Al[128 * 32];
    __shared__ __align__(16) unsigned short Bl[128 * 32];

    const int tid = threadIdx.x, lane = tid & 63, wv = tid >> 6;
    const int wm = (wv >> 1) * 64, wn = (wv & 1) * 64;
    const int l15 = lane & 15, g = lane >> 4;

    f32x4 zero4 = {0.f, 0.f, 0.f, 0.f};
    f32x4 acc[4][4];
#pragma unroll
    for (int i = 0; i < 4; ++i)
#pragma unroll
        for (int j = 0; j < 4; ++j) acc[i][j] = zero4;

    const unsigned short* Ab = P + (((size_t)(h * 2 + b)) * SB + Q0) * SB;
    const unsigned short* Bb = embT + ((size_t)(b * DD + nt * 128)) * SB;

    for (int k0 = klo; k0 < khi; k0 += 32) {
        __syncthreads();
#pragma unroll
        for (int s = 0; s < 2; ++s) {
            int e = (s * 256 + tid) * 8;
            int row = e >> 5, col = e & 31;
            __builtin_amdgcn_global_load_lds(as_gbl(Ab + (size_t)row * SB + k0 + col),
                                             as_lds(Al + e), 16, 0, 0);
            __builtin_amdgcn_global_load_lds(as_gbl(Bb + (size_t)row * SB + k0 + col),
                                             as_lds(Bl + e), 16, 0, 0);
        }
        asm volatile("s_waitcnt vmcnt(0)" ::: "memory");
        __syncthreads();

        bf16x8 af[4], bfr[4];
#pragma unroll
        for (int i = 0; i < 4; ++i) {
            af[i]  = *(const bf16x8*)(Al + (wm + i * 16 + l15) * 32 + 8 * g);
            bfr[i] = *(const bf16x8*)(Bl + (wn + i * 16 + l15) * 32 + 8 * g);
        }
#pragma unroll
        for (int i = 0; i < 4; ++i)
#pragma unroll
            for (int j = 0; j < 4; ++j)
                acc[i][j] = __builtin_amdgcn_mfma_f32_16x16x32_bf16(af[i], bfr[j], acc[i][j], 0, 0, 0);
    }

    const float* ls = lsum + ((size_t)(h * 2 + b)) * SB;
    unsigned short* cb = concat + ((size_t)(b * SB)) * (HH * DD) + h * DD + nt * 128;
#pragma unroll
    for (int i = 0; i < 4; ++i) {
        int rowb = wm + i * 16 + g * 4;
        float inv[4];
#pragma unroll
        for (int rr = 0; rr < 4; ++rr) inv[rr] = 1.f / ls[Q0 + rowb + rr];
#pragma unroll
        for (int j = 0; j < 4; ++j) {
            int col = wn + j * 16 + l15;
#pragma unroll
            for (int rr = 0; rr < 4; ++rr)
                cb[(size_t)(Q0 + rowb + rr) * (HH * DD) + col] = f2bf(acc[i][j][rr] * inv[rr]);
        }
    }
}

// ---------------- m97-style bf16 GEMM, B^T input, 128x128 tile, BK=32 ----------------
template <int OUTF32>
__launch_bounds__(256, 2)
__global__ void k_gemm_bt(const unsigned short* __restrict__ A,
                          const unsigned short* __restrict__ Bt,
                          const float* __restrict__ bias,
                          void* __restrict__ Cout,
                          int M, int N, int K)
{
    const int nMt = M >> 7;
    const int nwg = gridDim.x;
    int bid = blockIdx.x;
    int q = nwg >> 3, r = nwg & 7;
    int x = bid & 7, o = bid >> 3;
    int wg = (x < r ? x * (q + 1) : r * (q + 1) + (x - r) * q) + o;
    const int mt = wg % nMt, nt = wg / nMt;

    __shared__ __align__(16) unsigned short Al[128 * 32];
    __shared__ __align__(16) unsigned short Bl[128 * 32];

    const int tid = threadIdx.x;
    const int lane = tid & 63;
    const int wv = tid >> 6;
    const int wm = (wv >> 1) * 64, wn = (wv & 1) * 64;
    const int l15 = lane & 15, g = lane >> 4;

    f32x4 zero4 = {0.f, 0.f, 0.f, 0.f};
    f32x4 acc[4][4];
#pragma unroll
    for (int i = 0; i < 4; ++i)
#pragma unroll
        for (int j = 0; j < 4; ++j) acc[i][j] = zero4;

    const unsigned short* Ab = A + (size_t)mt * 128 * K;
    const unsigned short* Bb = Bt + (size_t)nt * 128 * K;

    for (int k0 = 0; k0 < K; k0 += 32) {
        __syncthreads();
#pragma unroll
        for (int s = 0; s < 2; ++s) {
            int e = (s * 256 + tid) * 8;
            int row = e >> 5, col = e & 31;
            __builtin_amdgcn_global_load_lds(as_gbl(Ab + (size_t)row * K + k0 + col),
                                             as_lds(Al + e), 16, 0, 0);
            __builtin_amdgcn_global_load_lds(as_gbl(Bb + (size_t)row * K + k0 + col),
                                             as_lds(Bl + e), 16, 0, 0);
        }
        asm volatile("s_waitcnt vmcnt(0)" ::: "memory");
        __syncthreads();

        bf16x8 af[4], bfr[4];
#pragma unroll
        for (int i = 0; i < 4; ++i) {
            af[i]  = *(const bf16x8*)(Al + (wm + i * 16 + l15) * 32 + 8 * g);
            bfr[i] = *(const bf16x8*)(Bl + (wn + i * 16 + l15) * 32 + 8 * g);
        }
#pragma unroll
        for (int i = 0; i < 4; ++i)
#pragma unroll
            for (int j = 0; j < 4; ++j)
                acc[i][j] = __builtin_amdgcn_mfma_f32_16x16x32_bf16(af[i], bfr[j], acc[i][j], 0, 0, 0);
    }

#pragma unroll
    for (int i = 0; i < 4; ++i) {
        int rowb = mt * 128 + wm + i * 16 + g * 4;
#pragma unroll
        for (int j = 0; j < 4; ++j) {
            int col = nt * 128 + wn + j * 16 + l15;
            float bv = bias[col];
            if (OUTF32) {
                float* C = (float*)Cout;
#pragma unroll
                for (int rr = 0; rr < 4; ++rr)
                    C[(size_t)(rowb + rr) * N + col] = acc[i][j][rr] + bv;
            } else {
                unsigned short* C = (unsigned short*)Cout;
#pragma unroll
                for (int rr = 0; rr < 4; ++rr)
                    C[(size_t)(rowb + rr) * N + col] = f2bf(acc[i][j][rr] + bv);
            }
        }
    }
}

extern "C" void kernel_launch(void* const* d_in, const int* in_sizes, int n_in,
                              void* d_out, int out_size, void* d_ws, size_t ws_size,
                              hipStream_t stream)
{
    const int*           ids = (const int*)d_in[0];
    const unsigned char* pad = (const unsigned char*)d_in[1];
    const float*         tbl = (const float*)d_in[2];
    const float*         sfs = (const float*)d_in[3];
    const float*         als = (const float*)d_in[4];
    const float*         fw  = (const float*)d_in[5];
    const float*         fb  = (const float*)d_in[6];
    const float*         ow  = (const float*)d_in[7];
    const float*         ob  = (const float*)d_in[8];
    float* logits = (float*)d_out;

    // d_ws layout (60 MB, unchanged from passing round)
    char* ws = (char*)d_ws;
    unsigned short* outw_bf = (unsigned short*)(ws);              // 32,768,000 B
    unsigned short* fusw_bf = (unsigned short*)(ws + 32768000);   //  2,097,152 B
    unsigned short* emb_bf  = (unsigned short*)(ws + 34865152);   //  4,194,304 B
    unsigned short* concat  = (unsigned short*)(ws + 39059456);   // 16,777,216 B
    unsigned short* fused   = (unsigned short*)(ws + 55836672);   //  4,194,304 B

    // scratch inside d_out (485 MB f32 logits; dead until final GEMM overwrites it)
    char* ob_scratch = (char*)d_out;
    unsigned short* P    = (unsigned short*)(ob_scratch);              // 67,108,864 B
    unsigned short* embT = (unsigned short*)(ob_scratch + 67108864);   //  4,194,304 B
    float*          dtab = (float*)(ob_scratch + 71303168);            //     32,768 B
    float*          lsum = (float*)(ob_scratch + 71335936);            //     65,536 B

    k_cvt_bf16<<<2048, 256, 0, stream>>>(ow, outw_bf, VV * DD);
    k_cvt_bf16<<<512, 256, 0, stream>>>(fw, fusw_bf, DD * HH * DD);
    k_embed<<<BB * SB, 256, 0, stream>>>(ids, tbl, emb_bf);
    k_dtab_lsum<<<96, 256, 0, stream>>>(als, dtab, lsum);

    dim3 tg(8, 32, BB);
    k_embT<<<tg, 256, 0, stream>>>(emb_bf, embT);

    dim3 bg(32, 32, BB);
    k_base<<<bg, 256, 0, stream>>>(emb_bf, pad, sfs, dtab, P, lsum);

    dim3 pg(64, BB, HH);
    k_pv<<<pg, 256, 0, stream>>>(P, embT, lsum, concat);

    k_gemm_bt<0><<<32 * 4, 256, 0, stream>>>(concat, fusw_bf, fb, fused, BB * SB, DD, HH * DD);
    k_gemm_bt<1><<<32 * 250, 256, 0, stream>>>(fused, outw_bf, ob, logits, BB * SB, VV, DD);
}

// Round 4
// 386.473 us; speedup vs baseline: 2.0121x; 1.0214x over previous
//
#include <hip/hip_runtime.h>
#include <hip/hip_bf16.h>
#include <stdint.h>

#define BB 2
#define SB 2048
#define DD 512
#define HH 4
#define VV 32000

typedef __attribute__((ext_vector_type(4))) float f32x4;
typedef __attribute__((ext_vector_type(8))) short bf16x8;
typedef __attribute__((ext_vector_type(4))) unsigned short us4;

__device__ __forceinline__ unsigned short f2bf(float f) {
    unsigned u = __float_as_uint(f);
    u += 0x7fffu + ((u >> 16) & 1u);
    return (unsigned short)(u >> 16);
}

__device__ __forceinline__ __attribute__((address_space(3))) unsigned int*
as_lds(void* p) {
    return (__attribute__((address_space(3))) unsigned int*)(unsigned)(uintptr_t)p;
}
__device__ __forceinline__ const __attribute__((address_space(1))) unsigned int*
as_gbl(const void* p) {
    return (const __attribute__((address_space(1))) unsigned int*)(uintptr_t)p;
}

// swizzled LDS read of a bf16x8 fragment: tile rows of 32 elems (64B), 16B-granule
// 2-bit XOR: chunk' = g ^ (row&3). Matches the inverse-swizzled staging source.
__device__ __forceinline__ bf16x8 ldsrd(const unsigned short* base, int row, int g) {
    int byte = row * 64 + (((g) ^ (row & 3)) << 4);
    return *(const bf16x8*)((const char*)base + byte);
}

// ---------------- merged prep kernel ----------------
// seg0 [0,2000): out_w f32->bf16 (16,384,000 elems, 8192/block)
// seg1 [2000,2256): fusion_w cvt (1,048,576 elems, 4096/block)
// seg2 [2256,6352): embedding gather+cvt (row per block)
// seg3 [6352,6448): dtab + lsum zero
// seg4 [6448,6960): embT tiles (gather directly from table, transpose)
__global__ void k_prep(const int* __restrict__ ids, const float* __restrict__ tbl,
                       const float* __restrict__ als,
                       const float* __restrict__ fw, const float* __restrict__ ow,
                       unsigned short* __restrict__ outw_bf, unsigned short* __restrict__ fusw_bf,
                       unsigned short* __restrict__ emb, unsigned short* __restrict__ embT,
                       float* __restrict__ dtab, float* __restrict__ lsum)
{
    __shared__ unsigned short TT[64][72];
    const int bid = blockIdx.x, t = threadIdx.x;

    if (bid < 2000) {
        int base = bid * 8192 + t * 4;
#pragma unroll
        for (int it = 0; it < 8; ++it) {
            int i = base + it * 1024;
            float4 v = *(const float4*)(ow + i);
            us4 o; o.x = f2bf(v.x); o.y = f2bf(v.y); o.z = f2bf(v.z); o.w = f2bf(v.w);
            *(us4*)(outw_bf + i) = o;
        }
    } else if (bid < 2256) {
        int base = (bid - 2000) * 4096 + t * 4;
#pragma unroll
        for (int it = 0; it < 4; ++it) {
            int i = base + it * 1024;
            float4 v = *(const float4*)(fw + i);
            us4 o; o.x = f2bf(v.x); o.y = f2bf(v.y); o.z = f2bf(v.z); o.w = f2bf(v.w);
            *(us4*)(fusw_bf + i) = o;
        }
    } else if (bid < 6352) {
        int row = bid - 2256;
        int id = ids[row];
        if (id < 0) id = 0;
        if (id >= VV) id = VV - 1;
        const float* s = tbl + (size_t)id * DD;
        unsigned short* d = emb + (size_t)row * DD;
        d[t]       = f2bf(s[t]);
        d[t + 256] = f2bf(s[t + 256]);
    } else if (bid < 6448) {
        int i = (bid - 6352) * 256 + t;
        if (i < HH * SB) {
            int h = i >> 11, dd = i & (SB - 1);
            dtab[i] = 0.04419417382415922f / (1.f + als[h] * (float)dd);
        } else {
            lsum[i - HH * SB] = 0.f;
        }
    } else {
        int bid2 = bid - 6448;
        const int d0 = (bid2 & 7) * 64, s0 = ((bid2 >> 3) & 31) * 64, b = bid2 >> 8;
        {
            int s = t >> 2, c16 = (t & 3) * 16;
            int id = ids[b * SB + s0 + s];
            if (id < 0) id = 0;
            if (id >= VV) id = VV - 1;
            const float* src = tbl + (size_t)id * DD + d0 + c16;
#pragma unroll
            for (int q4 = 0; q4 < 4; ++q4) {
                float4 v = *(const float4*)(src + q4 * 4);
                TT[c16 + q4 * 4 + 0][s] = f2bf(v.x);
                TT[c16 + q4 * 4 + 1][s] = f2bf(v.y);
                TT[c16 + q4 * 4 + 2][s] = f2bf(v.z);
                TT[c16 + q4 * 4 + 3][s] = f2bf(v.w);
            }
        }
        __syncthreads();
        {
            int d = t >> 2, sc = (t & 3) * 16;
            bf16x8 o0, o1;
#pragma unroll
            for (int j = 0; j < 8; ++j) {
                o0[j] = (short)TT[d][sc + j];
                o1[j] = (short)TT[d][sc + 8 + j];
            }
            unsigned short* dst = embT + ((size_t)(b * DD + d0 + d)) * SB + s0 + sc;
            *(bf16x8*)dst = o0;
            *(bf16x8*)(dst + 8) = o1;
        }
    }
}

// ---------------- phase 2: shared base QK^T -> per-head P tiles + row sums ----------------
__launch_bounds__(256, 2)
__global__ void k_base(const unsigned short* __restrict__ emb,
                       const unsigned char* __restrict__ pad,
                       const float* __restrict__ sfs,
                       const float* __restrict__ dtab,
                       unsigned short* __restrict__ P,      // [4][2][2048][2048]
                       float* __restrict__ lsum)            // [4][2][2048]
{
    const int kt = blockIdx.x, qt = blockIdx.y, b = blockIdx.z;
    if (kt > qt + 1) return;
    const int tid = threadIdx.x, lane = tid & 63, wv = tid >> 6;
    const int l15 = lane & 15, g = lane >> 4;

    if (kt == qt + 1) {
        int row = tid >> 2, cb = (tid & 3) * 16;
        int4 z = {0, 0, 0, 0};
#pragma unroll
        for (int h = 0; h < 4; ++h) {
            unsigned short* Ph = P + (((size_t)(h * 2 + b)) * SB + qt * 64 + row) * SB + kt * 64 + cb;
            *(int4*)Ph = z;
            *(int4*)(Ph + 8) = z;
        }
        return;
    }

    __shared__ __align__(16) unsigned short Ql[64 * 128];
    __shared__ __align__(16) unsigned short Kl[64 * 128];

    const int q = qt * 64 + wv * 16 + l15;

    f32x4 zero4 = {0.f, 0.f, 0.f, 0.f};
    f32x4 cc[4];
#pragma unroll
    for (int c = 0; c < 4; ++c) cc[c] = zero4;

    for (int dc = 0; dc < 4; ++dc) {
        const int d0 = dc * 128;
        __syncthreads();
#pragma unroll
        for (int i = 0; i < 4; ++i) {
            int flat = (i * 256 + tid) * 8;
            int row = flat >> 7;
            int ch  = (flat >> 3) & 15;
            int scol = ((ch ^ (row & 15)) << 3);
            __builtin_amdgcn_global_load_lds(
                as_gbl(emb + ((size_t)(b * SB + qt * 64 + row)) * DD + d0 + scol),
                as_lds(Ql + flat), 16, 0, 0);
            __builtin_amdgcn_global_load_lds(
                as_gbl(emb + ((size_t)(b * SB + kt * 64 + row)) * DD + d0 + scol),
                as_lds(Kl + flat), 16, 0, 0);
        }
        asm volatile("s_waitcnt vmcnt(0)" ::: "memory");
        __syncthreads();

#pragma unroll
        for (int dsl = 0; dsl < 4; ++dsl) {
            int chr = (dsl * 4 + g);
            bf16x8 qf = *(const bf16x8*)(Ql + (wv * 16 + l15) * 128 + ((chr ^ l15) << 3));
#pragma unroll
            for (int c = 0; c < 4; ++c) {
                bf16x8 kf = *(const bf16x8*)(Kl + (c * 16 + l15) * 128 + ((chr ^ l15) << 3));
                cc[c] = __builtin_amdgcn_mfma_f32_16x16x32_bf16(kf, qf, cc[c], 0, 0, 0);
            }
        }
    }

    unsigned long long padm = __ballot(pad[(size_t)b * SB + kt * 64 + lane] != 0);

    const int wins[4] = {1 << 30, 128, 512, 1 << 30};
#pragma unroll
    for (int h = 0; h < 4; ++h) {
        const int win = wins[h];
        if (kt * 64 + win + 192 < qt * 64) continue;
        const float sf = sfs[h];
        const float* dth = dtab + h * SB;
        float rsum = 0.f;
        unsigned short pb[4][4];
#pragma unroll
        for (int c = 0; c < 4; ++c) {
#pragma unroll
            for (int r = 0; r < 4; ++r) {
                int kk = kt * 64 + c * 16 + 4 * g + r;
                int dist = q - kk;
                float p = 0.f;
                if (dist >= 0 && dist <= win &&
                    ((dist == 0) || !((padm >> (c * 16 + 4 * g + r)) & 1ull))) {
                    float s = cc[c][r] * dth[dist];
                    if (dist == 0) s *= sf;
                    p = __expf(s);
                }
                rsum += p;
                pb[c][r] = f2bf(p);
            }
        }
        unsigned short* Ph = P + (((size_t)(h * 2 + b)) * SB + q) * SB + kt * 64;
#pragma unroll
        for (int c = 0; c < 4; ++c) {
            us4 o;
            o.x = pb[c][0]; o.y = pb[c][1]; o.z = pb[c][2]; o.w = pb[c][3];
            *(us4*)(Ph + c * 16 + 4 * g) = o;
        }
        rsum += __shfl_xor(rsum, 16, 64);
        rsum += __shfl_xor(rsum, 32, 64);
        if (lane < 16)
            atomicAdd(&lsum[((size_t)(h * 2 + b)) * SB + q], rsum);
    }
}

// ---------------- phase 3: ctx = P * V^T, normalize, write concat ----------------
__launch_bounds__(256, 2)
__global__ void k_pv(const unsigned short* __restrict__ P,
                     const unsigned short* __restrict__ embT,
                     const float* __restrict__ lsum,
                     unsigned short* __restrict__ concat)
{
    const int t64 = blockIdx.x, b = blockIdx.y, h = blockIdx.z;
    const int mt = t64 >> 2, nt = t64 & 3;
    const int Q0 = mt * 128;
    const int win = (h == 1) ? 128 : (h == 2) ? 512 : (1 << 30);
    int klo = Q0 - win - 64; if (klo < 0) klo = 0; klo &= ~63;
    const int khi = Q0 + 128;

    __shared__ __align__(16) unsigned short Al[128 * 32];
    __shared__ __align__(16) unsigned short Bl[128 * 32];

    const int tid = threadIdx.x, lane = tid & 63, wv = tid >> 6;
    const int wm = (wv >> 1) * 64, wn = (wv & 1) * 64;
    const int l15 = lane & 15, g = lane >> 4;

    f32x4 zero4 = {0.f, 0.f, 0.f, 0.f};
    f32x4 acc[4][4];
#pragma unroll
    for (int i = 0; i < 4; ++i)
#pragma unroll
        for (int j = 0; j < 4; ++j) acc[i][j] = zero4;

    const unsigned short* Ab = P + (((size_t)(h * 2 + b)) * SB + Q0) * SB;
    const unsigned short* Bb = embT + ((size_t)(b * DD + nt * 128)) * SB;

    for (int k0 = klo; k0 < khi; k0 += 32) {
        __syncthreads();
#pragma unroll
        for (int s = 0; s < 2; ++s) {
            int e = (s * 256 + tid) * 8;
            int row = e >> 5, col = e & 31;
            __builtin_amdgcn_global_load_lds(as_gbl(Ab + (size_t)row * SB + k0 + col),
                                             as_lds(Al + e), 16, 0, 0);
            __builtin_amdgcn_global_load_lds(as_gbl(Bb + (size_t)row * SB + k0 + col),
                                             as_lds(Bl + e), 16, 0, 0);
        }
        asm volatile("s_waitcnt vmcnt(0)" ::: "memory");
        __syncthreads();

        bf16x8 af[4], bfr[4];
#pragma unroll
        for (int i = 0; i < 4; ++i) {
            af[i]  = *(const bf16x8*)(Al + (wm + i * 16 + l15) * 32 + 8 * g);
            bfr[i] = *(const bf16x8*)(Bl + (wn + i * 16 + l15) * 32 + 8 * g);
        }
#pragma unroll
        for (int i = 0; i < 4; ++i)
#pragma unroll
            for (int j = 0; j < 4; ++j)
                acc[i][j] = __builtin_amdgcn_mfma_f32_16x16x32_bf16(af[i], bfr[j], acc[i][j], 0, 0, 0);
    }

    const float* ls = lsum + ((size_t)(h * 2 + b)) * SB;
    unsigned short* cb = concat + ((size_t)(b * SB)) * (HH * DD) + h * DD + nt * 128;
#pragma unroll
    for (int i = 0; i < 4; ++i) {
        int rowb = wm + i * 16 + g * 4;
        float inv[4];
#pragma unroll
        for (int rr = 0; rr < 4; ++rr) inv[rr] = 1.f / ls[Q0 + rowb + rr];
#pragma unroll
        for (int j = 0; j < 4; ++j) {
            int col = wn + j * 16 + l15;
#pragma unroll
            for (int rr = 0; rr < 4; ++rr)
                cb[(size_t)(Q0 + rowb + rr) * (HH * DD) + col] = f2bf(acc[i][j][rr] * inv[rr]);
        }
    }
}

// ---------------- m97-style 128x128 GEMM (kept for the small fusion GEMM) ----------------
template <int OUTF32>
__launch_bounds__(256, 2)
__global__ void k_gemm_bt(const unsigned short* __restrict__ A,
                          const unsigned short* __restrict__ Bt,
                          const float* __restrict__ bias,
                          void* __restrict__ Cout,
                          int M, int N, int K)
{
    const int nMt = M >> 7;
    const int nwg = gridDim.x;
    int bid = blockIdx.x;
    int q = nwg >> 3, r = nwg & 7;
    int x = bid & 7, o = bid >> 3;
    int wg = (x < r ? x * (q + 1) : r * (q + 1) + (x - r) * q) + o;
    const int mt = wg % nMt, nt = wg / nMt;

    __shared__ __align__(16) unsigned short Al[128 * 32];
    __shared__ __align__(16) unsigned short Bl[128 * 32];

    const int tid = threadIdx.x;
    const int lane = tid & 63;
    const int wv = tid >> 6;
    const int wm = (wv >> 1) * 64, wn = (wv & 1) * 64;
    const int l15 = lane & 15, g = lane >> 4;

    f32x4 zero4 = {0.f, 0.f, 0.f, 0.f};
    f32x4 acc[4][4];
#pragma unroll
    for (int i = 0; i < 4; ++i)
#pragma unroll
        for (int j = 0; j < 4; ++j) acc[i][j] = zero4;

    const unsigned short* Ab = A + (size_t)mt * 128 * K;
    const unsigned short* Bb = Bt + (size_t)nt * 128 * K;

    for (int k0 = 0; k0 < K; k0 += 32) {
        __syncthreads();
#pragma unroll
        for (int s = 0; s < 2; ++s) {
            int e = (s * 256 + tid) * 8;
            int row = e >> 5, col = e & 31;
            __builtin_amdgcn_global_load_lds(as_gbl(Ab + (size_t)row * K + k0 + col),
                                             as_lds(Al + e), 16, 0, 0);
            __builtin_amdgcn_global_load_lds(as_gbl(Bb + (size_t)row * K + k0 + col),
                                             as_lds(Bl + e), 16, 0, 0);
        }
        asm volatile("s_waitcnt vmcnt(0)" ::: "memory");
        __syncthreads();

        bf16x8 af[4], bfr[4];
#pragma unroll
        for (int i = 0; i < 4; ++i) {
            af[i]  = *(const bf16x8*)(Al + (wm + i * 16 + l15) * 32 + 8 * g);
            bfr[i] = *(const bf16x8*)(Bl + (wn + i * 16 + l15) * 32 + 8 * g);
        }
#pragma unroll
        for (int i = 0; i < 4; ++i)
#pragma unroll
            for (int j = 0; j < 4; ++j)
                acc[i][j] = __builtin_amdgcn_mfma_f32_16x16x32_bf16(af[i], bfr[j], acc[i][j], 0, 0, 0);
    }

#pragma unroll
    for (int i = 0; i < 4; ++i) {
        int rowb = mt * 128 + wm + i * 16 + g * 4;
#pragma unroll
        for (int j = 0; j < 4; ++j) {
            int col = nt * 128 + wn + j * 16 + l15;
            float bv = bias[col];
            if (OUTF32) {
                float* C = (float*)Cout;
#pragma unroll
                for (int rr = 0; rr < 4; ++rr)
                    C[(size_t)(rowb + rr) * N + col] = acc[i][j][rr] + bv;
            } else {
                unsigned short* C = (unsigned short*)Cout;
#pragma unroll
                for (int rr = 0; rr < 4; ++rr)
                    C[(size_t)(rowb + rr) * N + col] = f2bf(acc[i][j][rr] + bv);
            }
        }
    }
}

// ---------------- 256x256 deep-pipelined GEMM: BK=32, ring-4 LDS, counted vmcnt ----------------
// 512 threads = 8 waves (2 Mrows x 4 Ncols of 128x64 each). f32 out + bias.
__launch_bounds__(512, 2)
__global__ void k_gemm256(const unsigned short* __restrict__ A,
                          const unsigned short* __restrict__ Bt,
                          const float* __restrict__ bias,
                          float* __restrict__ Cout,
                          int M, int N, int K)
{
    const int nMt = M >> 8;
    const int nwg = gridDim.x;
    int bid = blockIdx.x;
    int q = nwg >> 3, r = nwg & 7;
    int x = bid & 7, o = bid >> 3;
    int wg = (x < r ? x * (q + 1) : r * (q + 1) + (x - r) * q) + o;
    const int mt = wg % nMt, nt = wg / nMt;

    __shared__ __align__(16) unsigned short Al[4][8192];   // ring of 256x32 tiles
    __shared__ __align__(16) unsigned short Bl[4][8192];

    const int tid = threadIdx.x;
    const int lane = tid & 63, wv = tid >> 6;
    const int wr = wv >> 2, wc = wv & 3;
    const int l15 = lane & 15, g = lane >> 4;

    f32x4 zero4 = {0.f, 0.f, 0.f, 0.f};
    f32x4 acc[8][4];
#pragma unroll
    for (int i = 0; i < 8; ++i)
#pragma unroll
        for (int j = 0; j < 4; ++j) acc[i][j] = zero4;

    const unsigned short* Ab = A + (size_t)mt * 256 * K;
    const unsigned short* Bb = Bt + (size_t)nt * 256 * K;

    // staging geometry: chunk c (16B) -> LDS linear; source col pre-inverse-swizzled
    const int c0 = tid, c1 = 512 + tid;
    const int r0 = c0 >> 2, r1 = c1 >> 2;
    const int sc0 = (((c0 & 3) ^ (r0 & 3)) << 3);
    const int sc1 = (((c1 & 3) ^ (r1 & 3)) << 3);
    const unsigned short* Asrc0 = Ab + (size_t)r0 * K + sc0;
    const unsigned short* Asrc1 = Ab + (size_t)r1 * K + sc1;
    const unsigned short* Bsrc0 = Bb + (size_t)r0 * K + sc0;
    const unsigned short* Bsrc1 = Bb + (size_t)r1 * K + sc1;

#define STAGE_A256(rg_, ko_) { \
    __builtin_amdgcn_global_load_lds(as_gbl(Asrc0 + (ko_)), as_lds(&Al[rg_][c0 * 8]), 16, 0, 0); \
    __builtin_amdgcn_global_load_lds(as_gbl(Asrc1 + (ko_)), as_lds(&Al[rg_][c1 * 8]), 16, 0, 0); }
#define STAGE_B256(rg_, ko_) { \
    __builtin_amdgcn_global_load_lds(as_gbl(Bsrc0 + (ko_)), as_lds(&Bl[rg_][c0 * 8]), 16, 0, 0); \
    __builtin_amdgcn_global_load_lds(as_gbl(Bsrc1 + (ko_)), as_lds(&Bl[rg_][c1 * 8]), 16, 0, 0); }

#define SBAR { __builtin_amdgcn_sched_barrier(0); __builtin_amdgcn_s_barrier(); __builtin_amdgcn_sched_barrier(0); }

#define GEMM_GROUP(t_, DOSTAGE_, WAIT_)                                          \
  {                                                                              \
    const int rg = (t_) & 3;                                                     \
    const unsigned short* Ar = Al[rg];                                           \
    const unsigned short* Br = Bl[rg];                                           \
    bf16x8 bfr0 = ldsrd(Br, wc * 64 +  0 + l15, g);                              \
    bf16x8 bfr1 = ldsrd(Br, wc * 64 + 16 + l15, g);                              \
    bf16x8 bfr2 = ldsrd(Br, wc * 64 + 32 + l15, g);                              \
    bf16x8 bfr3 = ldsrd(Br, wc * 64 + 48 + l15, g);                              \
    bf16x8 af0 = ldsrd(Ar, wr * 128 +  0 + l15, g);                              \
    bf16x8 af1 = ldsrd(Ar, wr * 128 + 16 + l15, g);                              \
    bf16x8 af2 = ldsrd(Ar, wr * 128 + 32 + l15, g);                              \
    bf16x8 af3 = ldsrd(Ar, wr * 128 + 48 + l15, g);                              \
    if (DOSTAGE_) STAGE_A256(((t_) + 3) & 3, ((t_) + 3) * 32);                   \
    SBAR;                                                                        \
    __builtin_amdgcn_s_setprio(1);                                               \
    acc[0][0] = __builtin_amdgcn_mfma_f32_16x16x32_bf16(af0, bfr0, acc[0][0], 0, 0, 0); \
    acc[0][1] = __builtin_amdgcn_mfma_f32_16x16x32_bf16(af0, bfr1, acc[0][1], 0, 0, 0); \
    acc[0][2] = __builtin_amdgcn_mfma_f32_16x16x32_bf16(af0, bfr2, acc[0][2], 0, 0, 0); \
    acc[0][3] = __builtin_amdgcn_mfma_f32_16x16x32_bf16(af0, bfr3, acc[0][3], 0, 0, 0); \
    acc[1][0] = __builtin_amdgcn_mfma_f32_16x16x32_bf16(af1, bfr0, acc[1][0], 0, 0, 0); \
    acc[1][1] = __builtin_amdgcn_mfma_f32_16x16x32_bf16(af1, bfr1, acc[1][1], 0, 0, 0); \
    acc[1][2] = __builtin_amdgcn_mfma_f32_16x16x32_bf16(af1, bfr2, acc[1][2], 0, 0, 0); \
    acc[1][3] = __builtin_amdgcn_mfma_f32_16x16x32_bf16(af1, bfr3, acc[1][3], 0, 0, 0); \
    acc[2][0] = __builtin_amdgcn_mfma_f32_16x16x32_bf16(af2, bfr0, acc[2][0], 0, 0, 0); \
    acc[2][1] = __builtin_amdgcn_mfma_f32_16x16x32_bf16(af2, bfr1, acc[2][1], 0, 0, 0); \
    acc[2][2] = __builtin_amdgcn_mfma_f32_16x16x32_bf16(af2, bfr2, acc[2][2], 0, 0, 0); \
    acc[2][3] = __builtin_amdgcn_mfma_f32_16x16x32_bf16(af2, bfr3, acc[2][3], 0, 0, 0); \
    acc[3][0] = __builtin_amdgcn_mfma_f32_16x16x32_bf16(af3, bfr0, acc[3][0], 0, 0, 0); \
    acc[3][1] = __builtin_amdgcn_mfma_f32_16x16x32_bf16(af3, bfr1, acc[3][1], 0, 0, 0); \
    acc[3][2] = __builtin_amdgcn_mfma_f32_16x16x32_bf16(af3, bfr2, acc[3][2], 0, 0, 0); \
    acc[3][3] = __builtin_amdgcn_mfma_f32_16x16x32_bf16(af3, bfr3, acc[3][3], 0, 0, 0); \
    __builtin_amdgcn_s_setprio(0);                                               \
    SBAR;                                                                        \
    bf16x8 ag0 = ldsrd(Ar, wr * 128 +  64 + l15, g);                             \
    bf16x8 ag1 = ldsrd(Ar, wr * 128 +  80 + l15, g);                             \
    bf16x8 ag2 = ldsrd(Ar, wr * 128 +  96 + l15, g);                             \
    bf16x8 ag3 = ldsrd(Ar, wr * 128 + 112 + l15, g);                             \
    if (DOSTAGE_) STAGE_B256(((t_) + 3) & 3, ((t_) + 3) * 32);                   \
    WAIT_;                                                                       \
    SBAR;                                                                        \
    __builtin_amdgcn_s_setprio(1);                                               \
    acc[4][0] = __builtin_amdgcn_mfma_f32_16x16x32_bf16(ag0, bfr0, acc[4][0], 0, 0, 0); \
    acc[4][1] = __builtin_amdgcn_mfma_f32_16x16x32_bf16(ag0, bfr1, acc[4][1], 0, 0, 0); \
    acc[4][2] = __builtin_amdgcn_mfma_f32_16x16x32_bf16(ag0, bfr2, acc[4][2], 0, 0, 0); \
    acc[4][3] = __builtin_amdgcn_mfma_f32_16x16x32_bf16(ag0, bfr3, acc[4][3], 0, 0, 0); \
    acc[5][0] = __builtin_amdgcn_mfma_f32_16x16x32_bf16(ag1, bfr0, acc[5][0], 0, 0, 0); \
    acc[5][1] = __builtin_amdgcn_mfma_f32_16x16x32_bf16(ag1, bfr1, acc[5][1], 0, 0, 0); \
    acc[5][2] = __builtin_amdgcn_mfma_f32_16x16x32_bf16(ag1, bfr2, acc[5][2], 0, 0, 0); \
    acc[5][3] = __builtin_amdgcn_mfma_f32_16x16x32_bf16(ag1, bfr3, acc[5][3], 0, 0, 0); \
    acc[6][0] = __builtin_amdgcn_mfma_f32_16x16x32_bf16(ag2, bfr0, acc[6][0], 0, 0, 0); \
    acc[6][1] = __builtin_amdgcn_mfma_f32_16x16x32_bf16(ag2, bfr1, acc[6][1], 0, 0, 0); \
    acc[6][2] = __builtin_amdgcn_mfma_f32_16x16x32_bf16(ag2, bfr2, acc[6][2], 0, 0, 0); \
    acc[6][3] = __builtin_amdgcn_mfma_f32_16x16x32_bf16(ag2, bfr3, acc[6][3], 0, 0, 0); \
    acc[7][0] = __builtin_amdgcn_mfma_f32_16x16x32_bf16(ag3, bfr0, acc[7][0], 0, 0, 0); \
    acc[7][1] = __builtin_amdgcn_mfma_f32_16x16x32_bf16(ag3, bfr1, acc[7][1], 0, 0, 0); \
    acc[7][2] = __builtin_amdgcn_mfma_f32_16x16x32_bf16(ag3, bfr2, acc[7][2], 0, 0, 0); \
    acc[7][3] = __builtin_amdgcn_mfma_f32_16x16x32_bf16(ag3, bfr3, acc[7][3], 0, 0, 0); \
    __builtin_amdgcn_s_setprio(0);                                               \
    SBAR;                                                                        \
  }

    const int NT = K >> 5;
    // prologue: stage tiles 0,1,2 ; wait until tile 0 (oldest 4 loads) landed
    STAGE_A256(0, 0);  STAGE_B256(0, 0);
    STAGE_A256(1, 32); STAGE_B256(1, 32);
    STAGE_A256(2, 64); STAGE_B256(2, 64);
    asm volatile("s_waitcnt vmcnt(8)" ::: "memory");
    SBAR;

    for (int t = 0; t < NT - 3; ++t) {
        GEMM_GROUP(t, 1, asm volatile("s_waitcnt vmcnt(8)" ::: "memory"));
    }
    GEMM_GROUP(NT - 3, 0, asm volatile("s_waitcnt vmcnt(4)" ::: "memory"));
    GEMM_GROUP(NT - 2, 0, asm volatile("s_waitcnt vmcnt(0)" ::: "memory"));
    GEMM_GROUP(NT - 1, 0, );

    // epilogue: bias + f32 store
    const int mrow = mt * 256 + wr * 128;
    const int ncol = nt * 256 + wc * 64;
#pragma unroll
    for (int i = 0; i < 8; ++i) {
        int rowb = mrow + i * 16 + g * 4;
#pragma unroll
        for (int j = 0; j < 4; ++j) {
            int col = ncol + j * 16 + l15;
            float bv = bias[col];
#pragma unroll
            for (int rr = 0; rr < 4; ++rr)
                Cout[(size_t)(rowb + rr) * N + col] = acc[i][j][rr] + bv;
        }
    }
#undef GEMM_GROUP
#undef STAGE_A256
#undef STAGE_B256
#undef SBAR
}

extern "C" void kernel_launch(void* const* d_in, const int* in_sizes, int n_in,
                              void* d_out, int out_size, void* d_ws, size_t ws_size,
                              hipStream_t stream)
{
    const int*           ids = (const int*)d_in[0];
    const unsigned char* pad = (const unsigned char*)d_in[1];
    const float*         tbl = (const float*)d_in[2];
    const float*         sfs = (const float*)d_in[3];
    const float*         als = (const float*)d_in[4];
    const float*         fw  = (const float*)d_in[5];
    const float*         fb  = (const float*)d_in[6];
    const float*         ow  = (const float*)d_in[7];
    const float*         ob  = (const float*)d_in[8];
    float* logits = (float*)d_out;

    // d_ws layout (60 MB)
    char* ws = (char*)d_ws;
    unsigned short* outw_bf = (unsigned short*)(ws);              // 32,768,000 B
    unsigned short* fusw_bf = (unsigned short*)(ws + 32768000);   //  2,097,152 B
    unsigned short* emb_bf  = (unsigned short*)(ws + 34865152);   //  4,194,304 B
    unsigned short* concat  = (unsigned short*)(ws + 39059456);   // 16,777,216 B
    unsigned short* fused   = (unsigned short*)(ws + 55836672);   //  4,194,304 B

    // scratch inside d_out (dead until final GEMM overwrites it)
    char* ob_scratch = (char*)d_out;
    unsigned short* P    = (unsigned short*)(ob_scratch);              // 67,108,864 B
    unsigned short* embT = (unsigned short*)(ob_scratch + 67108864);   //  4,194,304 B
    float*          dtab = (float*)(ob_scratch + 71303168);            //     32,768 B
    float*          lsum = (float*)(ob_scratch + 71335936);            //     65,536 B

    k_prep<<<6960, 256, 0, stream>>>(ids, tbl, als, fw, ow,
                                     outw_bf, fusw_bf, emb_bf, embT, dtab, lsum);

    dim3 bg(32, 32, BB);
    k_base<<<bg, 256, 0, stream>>>(emb_bf, pad, sfs, dtab, P, lsum);

    dim3 pg(64, BB, HH);
    k_pv<<<pg, 256, 0, stream>>>(P, embT, lsum, concat);

    k_gemm_bt<0><<<32 * 4, 256, 0, stream>>>(concat, fusw_bf, fb, fused, BB * SB, DD, HH * DD);
    k_gemm256<<<16 * 125, 512, 0, stream>>>(fused, outw_bf, ob, logits, BB * SB, VV, DD);
}

// Round 5
// 379.616 us; speedup vs baseline: 2.0485x; 1.0181x over previous
//
#include <hip/hip_runtime.h>
#include <hip/hip_bf16.h>
#include <stdint.h>

#define BB 2
#define SB 2048
#define DD 512
#define HH 4
#define VV 32000

typedef __attribute__((ext_vector_type(4))) float f32x4;
typedef __attribute__((ext_vector_type(8))) short bf16x8;
typedef __attribute__((ext_vector_type(4))) unsigned short us4;

__device__ __forceinline__ unsigned short f2bf(float f) {
    unsigned u = __float_as_uint(f);
    u += 0x7fffu + ((u >> 16) & 1u);
    return (unsigned short)(u >> 16);
}

__device__ __forceinline__ __attribute__((address_space(3))) unsigned int*
as_lds(void* p) {
    return (__attribute__((address_space(3))) unsigned int*)(unsigned)(uintptr_t)p;
}
__device__ __forceinline__ const __attribute__((address_space(1))) unsigned int*
as_gbl(const void* p) {
    return (const __attribute__((address_space(1))) unsigned int*)(uintptr_t)p;
}

// swizzled read from a [rows][64] bf16 LDS tile (128B rows): logical 16B-chunk c
// lives at slot c^(row&7). 16 lanes (same c, rows r..r+15) hit 8 slots x2 = 2-way free.
__device__ __forceinline__ bf16x8 ldsrd64(const unsigned short* base, int row, int c) {
    return *(const bf16x8*)((const char*)base + row * 128 + ((c ^ (row & 7)) << 4));
}

// ---------------- merged prep kernel ----------------
__global__ void k_prep(const int* __restrict__ ids, const float* __restrict__ tbl,
                       const float* __restrict__ als,
                       const float* __restrict__ fw, const float* __restrict__ ow,
                       unsigned short* __restrict__ outw_bf, unsigned short* __restrict__ fusw_bf,
                       unsigned short* __restrict__ emb, unsigned short* __restrict__ embT,
                       float* __restrict__ dtab, float* __restrict__ lsum)
{
    __shared__ unsigned short TT[64][72];
    const int bid = blockIdx.x, t = threadIdx.x;

    if (bid < 2000) {
        int base = bid * 8192 + t * 4;
#pragma unroll
        for (int it = 0; it < 8; ++it) {
            int i = base + it * 1024;
            float4 v = *(const float4*)(ow + i);
            us4 o; o.x = f2bf(v.x); o.y = f2bf(v.y); o.z = f2bf(v.z); o.w = f2bf(v.w);
            *(us4*)(outw_bf + i) = o;
        }
    } else if (bid < 2256) {
        int base = (bid - 2000) * 4096 + t * 4;
#pragma unroll
        for (int it = 0; it < 4; ++it) {
            int i = base + it * 1024;
            float4 v = *(const float4*)(fw + i);
            us4 o; o.x = f2bf(v.x); o.y = f2bf(v.y); o.z = f2bf(v.z); o.w = f2bf(v.w);
            *(us4*)(fusw_bf + i) = o;
        }
    } else if (bid < 6352) {
        int row = bid - 2256;
        int id = ids[row];
        if (id < 0) id = 0;
        if (id >= VV) id = VV - 1;
        const float* s = tbl + (size_t)id * DD;
        unsigned short* d = emb + (size_t)row * DD;
        d[t]       = f2bf(s[t]);
        d[t + 256] = f2bf(s[t + 256]);
    } else if (bid < 6448) {
        int i = (bid - 6352) * 256 + t;
        if (i < HH * SB) {
            int h = i >> 11, dd = i & (SB - 1);
            dtab[i] = 0.04419417382415922f / (1.f + als[h] * (float)dd);
        } else {
            lsum[i - HH * SB] = 0.f;
        }
    } else {
        int bid2 = bid - 6448;
        const int d0 = (bid2 & 7) * 64, s0 = ((bid2 >> 3) & 31) * 64, b = bid2 >> 8;
        {
            int s = t >> 2, c16 = (t & 3) * 16;
            int id = ids[b * SB + s0 + s];
            if (id < 0) id = 0;
            if (id >= VV) id = VV - 1;
            const float* src = tbl + (size_t)id * DD + d0 + c16;
#pragma unroll
            for (int q4 = 0; q4 < 4; ++q4) {
                float4 v = *(const float4*)(src + q4 * 4);
                TT[c16 + q4 * 4 + 0][s] = f2bf(v.x);
                TT[c16 + q4 * 4 + 1][s] = f2bf(v.y);
                TT[c16 + q4 * 4 + 2][s] = f2bf(v.z);
                TT[c16 + q4 * 4 + 3][s] = f2bf(v.w);
            }
        }
        __syncthreads();
        {
            int d = t >> 2, sc = (t & 3) * 16;
            bf16x8 o0, o1;
#pragma unroll
            for (int j = 0; j < 8; ++j) {
                o0[j] = (short)TT[d][sc + j];
                o1[j] = (short)TT[d][sc + 8 + j];
            }
            unsigned short* dst = embT + ((size_t)(b * DD + d0 + d)) * SB + s0 + sc;
            *(bf16x8*)dst = o0;
            *(bf16x8*)(dst + 8) = o1;
        }
    }
}

// ---------------- phase 2: shared base QK^T -> per-head P tiles + row sums ----------------
__launch_bounds__(256, 2)
__global__ void k_base(const unsigned short* __restrict__ emb,
                       const unsigned char* __restrict__ pad,
                       const float* __restrict__ sfs,
                       const float* __restrict__ dtab,
                       unsigned short* __restrict__ P,      // [4][2][2048][2048]
                       float* __restrict__ lsum)            // [4][2][2048]
{
    const int kt = blockIdx.x, qt = blockIdx.y, b = blockIdx.z;
    if (kt > qt + 1) return;
    const int tid = threadIdx.x, lane = tid & 63, wv = tid >> 6;
    const int l15 = lane & 15, g = lane >> 4;

    if (kt == qt + 1) {
        int row = tid >> 2, cb = (tid & 3) * 16;
        int4 z = {0, 0, 0, 0};
#pragma unroll
        for (int h = 0; h < 4; ++h) {
            unsigned short* Ph = P + (((size_t)(h * 2 + b)) * SB + qt * 64 + row) * SB + kt * 64 + cb;
            *(int4*)Ph = z;
            *(int4*)(Ph + 8) = z;
        }
        return;
    }

    __shared__ __align__(16) unsigned short Ql[64 * 128];
    __shared__ __align__(16) unsigned short Kl[64 * 128];

    const int q = qt * 64 + wv * 16 + l15;

    f32x4 zero4 = {0.f, 0.f, 0.f, 0.f};
    f32x4 cc[4];
#pragma unroll
    for (int c = 0; c < 4; ++c) cc[c] = zero4;

    for (int dc = 0; dc < 4; ++dc) {
        const int d0 = dc * 128;
        __syncthreads();
#pragma unroll
        for (int i = 0; i < 4; ++i) {
            int flat = (i * 256 + tid) * 8;
            int row = flat >> 7;
            int ch  = (flat >> 3) & 15;
            int scol = ((ch ^ (row & 15)) << 3);
            __builtin_amdgcn_global_load_lds(
                as_gbl(emb + ((size_t)(b * SB + qt * 64 + row)) * DD + d0 + scol),
                as_lds(Ql + flat), 16, 0, 0);
            __builtin_amdgcn_global_load_lds(
                as_gbl(emb + ((size_t)(b * SB + kt * 64 + row)) * DD + d0 + scol),
                as_lds(Kl + flat), 16, 0, 0);
        }
        asm volatile("s_waitcnt vmcnt(0)" ::: "memory");
        __syncthreads();

#pragma unroll
        for (int dsl = 0; dsl < 4; ++dsl) {
            int chr = (dsl * 4 + g);
            bf16x8 qf = *(const bf16x8*)(Ql + (wv * 16 + l15) * 128 + ((chr ^ l15) << 3));
#pragma unroll
            for (int c = 0; c < 4; ++c) {
                bf16x8 kf = *(const bf16x8*)(Kl + (c * 16 + l15) * 128 + ((chr ^ l15) << 3));
                cc[c] = __builtin_amdgcn_mfma_f32_16x16x32_bf16(kf, qf, cc[c], 0, 0, 0);
            }
        }
    }

    unsigned long long padm = __ballot(pad[(size_t)b * SB + kt * 64 + lane] != 0);

    const int wins[4] = {1 << 30, 128, 512, 1 << 30};
#pragma unroll
    for (int h = 0; h < 4; ++h) {
        const int win = wins[h];
        if (kt * 64 + win + 192 < qt * 64) continue;
        const float sf = sfs[h];
        const float* dth = dtab + h * SB;
        float rsum = 0.f;
        unsigned short pb[4][4];
#pragma unroll
        for (int c = 0; c < 4; ++c) {
#pragma unroll
            for (int r = 0; r < 4; ++r) {
                int kk = kt * 64 + c * 16 + 4 * g + r;
                int dist = q - kk;
                float p = 0.f;
                if (dist >= 0 && dist <= win &&
                    ((dist == 0) || !((padm >> (c * 16 + 4 * g + r)) & 1ull))) {
                    float s = cc[c][r] * dth[dist];
                    if (dist == 0) s *= sf;
                    p = __expf(s);
                }
                rsum += p;
                pb[c][r] = f2bf(p);
            }
        }
        unsigned short* Ph = P + (((size_t)(h * 2 + b)) * SB + q) * SB + kt * 64;
#pragma unroll
        for (int c = 0; c < 4; ++c) {
            us4 o;
            o.x = pb[c][0]; o.y = pb[c][1]; o.z = pb[c][2]; o.w = pb[c][3];
            *(us4*)(Ph + c * 16 + 4 * g) = o;
        }
        rsum += __shfl_xor(rsum, 16, 64);
        rsum += __shfl_xor(rsum, 32, 64);
        if (lane < 16)
            atomicAdd(&lsum[((size_t)(h * 2 + b)) * SB + q], rsum);
    }
}

// ---------------- phase 3: ctx = P * V^T, normalize, write concat ----------------
__launch_bounds__(256, 2)
__global__ void k_pv(const unsigned short* __restrict__ P,
                     const unsigned short* __restrict__ embT,
                     const float* __restrict__ lsum,
                     unsigned short* __restrict__ concat)
{
    const int t64 = blockIdx.x, b = blockIdx.y, h = blockIdx.z;
    const int mt = t64 >> 2, nt = t64 & 3;
    const int Q0 = mt * 128;
    const int win = (h == 1) ? 128 : (h == 2) ? 512 : (1 << 30);
    int klo = Q0 - win - 64; if (klo < 0) klo = 0; klo &= ~63;
    const int khi = Q0 + 128;

    __shared__ __align__(16) unsigned short Al[128 * 32];
    __shared__ __align__(16) unsigned short Bl[128 * 32];

    const int tid = threadIdx.x, lane = tid & 63, wv = tid >> 6;
    const int wm = (wv >> 1) * 64, wn = (wv & 1) * 64;
    const int l15 = lane & 15, g = lane >> 4;

    f32x4 zero4 = {0.f, 0.f, 0.f, 0.f};
    f32x4 acc[4][4];
#pragma unroll
    for (int i = 0; i < 4; ++i)
#pragma unroll
        for (int j = 0; j < 4; ++j) acc[i][j] = zero4;

    const unsigned short* Ab = P + (((size_t)(h * 2 + b)) * SB + Q0) * SB;
    const unsigned short* Bb = embT + ((size_t)(b * DD + nt * 128)) * SB;

    for (int k0 = klo; k0 < khi; k0 += 32) {
        __syncthreads();
#pragma unroll
        for (int s = 0; s < 2; ++s) {
            int e = (s * 256 + tid) * 8;
            int row = e >> 5, col = e & 31;
            __builtin_amdgcn_global_load_lds(as_gbl(Ab + (size_t)row * SB + k0 + col),
                                             as_lds(Al + e), 16, 0, 0);
            __builtin_amdgcn_global_load_lds(as_gbl(Bb + (size_t)row * SB + k0 + col),
                                             as_lds(Bl + e), 16, 0, 0);
        }
        asm volatile("s_waitcnt vmcnt(0)" ::: "memory");
        __syncthreads();

        bf16x8 af[4], bfr[4];
#pragma unroll
        for (int i = 0; i < 4; ++i) {
            af[i]  = *(const bf16x8*)(Al + (wm + i * 16 + l15) * 32 + 8 * g);
            bfr[i] = *(const bf16x8*)(Bl + (wn + i * 16 + l15) * 32 + 8 * g);
        }
#pragma unroll
        for (int i = 0; i < 4; ++i)
#pragma unroll
            for (int j = 0; j < 4; ++j)
                acc[i][j] = __builtin_amdgcn_mfma_f32_16x16x32_bf16(af[i], bfr[j], acc[i][j], 0, 0, 0);
    }

    const float* ls = lsum + ((size_t)(h * 2 + b)) * SB;
    unsigned short* cb = concat + ((size_t)(b * SB)) * (HH * DD) + h * DD + nt * 128;
#pragma unroll
    for (int i = 0; i < 4; ++i) {
        int rowb = wm + i * 16 + g * 4;
        float inv[4];
#pragma unroll
        for (int rr = 0; rr < 4; ++rr) inv[rr] = 1.f / ls[Q0 + rowb + rr];
#pragma unroll
        for (int j = 0; j < 4; ++j) {
            int col = wn + j * 16 + l15;
#pragma unroll
            for (int rr = 0; rr < 4; ++rr)
                cb[(size_t)(Q0 + rowb + rr) * (HH * DD) + col] = f2bf(acc[i][j][rr] * inv[rr]);
        }
    }
}

// ---------------- m97-style 128x128 GEMM (fusion GEMM) ----------------
template <int OUTF32>
__launch_bounds__(256, 2)
__global__ void k_gemm_bt(const unsigned short* __restrict__ A,
                          const unsigned short* __restrict__ Bt,
                          const float* __restrict__ bias,
                          void* __restrict__ Cout,
                          int M, int N, int K)
{
    const int nMt = M >> 7;
    const int nwg = gridDim.x;
    int bid = blockIdx.x;
    int q = nwg >> 3, r = nwg & 7;
    int x = bid & 7, o = bid >> 3;
    int wg = (x < r ? x * (q + 1) : r * (q + 1) + (x - r) * q) + o;
    const int mt = wg % nMt, nt = wg / nMt;

    __shared__ __align__(16) unsigned short Al[128 * 32];
    __shared__ __align__(16) unsigned short Bl[128 * 32];

    const int tid = threadIdx.x;
    const int lane = tid & 63;
    const int wv = tid >> 6;
    const int wm = (wv >> 1) * 64, wn = (wv & 1) * 64;
    const int l15 = lane & 15, g = lane >> 4;

    f32x4 zero4 = {0.f, 0.f, 0.f, 0.f};
    f32x4 acc[4][4];
#pragma unroll
    for (int i = 0; i < 4; ++i)
#pragma unroll
        for (int j = 0; j < 4; ++j) acc[i][j] = zero4;

    const unsigned short* Ab = A + (size_t)mt * 128 * K;
    const unsigned short* Bb = Bt + (size_t)nt * 128 * K;

    for (int k0 = 0; k0 < K; k0 += 32) {
        __syncthreads();
#pragma unroll
        for (int s = 0; s < 2; ++s) {
            int e = (s * 256 + tid) * 8;
            int row = e >> 5, col = e & 31;
            __builtin_amdgcn_global_load_lds(as_gbl(Ab + (size_t)row * K + k0 + col),
                                             as_lds(Al + e), 16, 0, 0);
            __builtin_amdgcn_global_load_lds(as_gbl(Bb + (size_t)row * K + k0 + col),
                                             as_lds(Bl + e), 16, 0, 0);
        }
        asm volatile("s_waitcnt vmcnt(0)" ::: "memory");
        __syncthreads();

        bf16x8 af[4], bfr[4];
#pragma unroll
        for (int i = 0; i < 4; ++i) {
            af[i]  = *(const bf16x8*)(Al + (wm + i * 16 + l15) * 32 + 8 * g);
            bfr[i] = *(const bf16x8*)(Bl + (wn + i * 16 + l15) * 32 + 8 * g);
        }
#pragma unroll
        for (int i = 0; i < 4; ++i)
#pragma unroll
            for (int j = 0; j < 4; ++j)
                acc[i][j] = __builtin_amdgcn_mfma_f32_16x16x32_bf16(af[i], bfr[j], acc[i][j], 0, 0, 0);
    }

#pragma unroll
    for (int i = 0; i < 4; ++i) {
        int rowb = mt * 128 + wm + i * 16 + g * 4;
#pragma unroll
        for (int j = 0; j < 4; ++j) {
            int col = nt * 128 + wn + j * 16 + l15;
            float bv = bias[col];
            if (OUTF32) {
                float* C = (float*)Cout;
#pragma unroll
                for (int rr = 0; rr < 4; ++rr)
                    C[(size_t)(rowb + rr) * N + col] = acc[i][j][rr] + bv;
            } else {
                unsigned short* C = (unsigned short*)Cout;
#pragma unroll
                for (int rr = 0; rr < 4; ++rr)
                    C[(size_t)(rowb + rr) * N + col] = f2bf(acc[i][j][rr] + bv);
            }
        }
    }
}

// ---------------- logits GEMM: 256x256 tile, BK=64, double-buffer, 1 barrier/K-step ----
// 512 threads = 8 waves (2Mr x 4Nc of 128x64). 64 MFMA + 24 ds_read/wave per barrier.
__launch_bounds__(512, 1)
__global__ void k_logits(const unsigned short* __restrict__ A,
                         const unsigned short* __restrict__ Bt,
                         const float* __restrict__ bias,
                         float* __restrict__ Cout,
                         int M, int N, int K)
{
    const int nMt = M >> 8;
    const int nwg = gridDim.x;
    int bid = blockIdx.x;
    int q = nwg >> 3, r = nwg & 7;
    int x = bid & 7, o = bid >> 3;
    int wg = (x < r ? x * (q + 1) : r * (q + 1) + (x - r) * q) + o;
    const int mt = wg % nMt, nt = wg / nMt;

    __shared__ __align__(16) unsigned short Al[2][256 * 64];
    __shared__ __align__(16) unsigned short Bl[2][256 * 64];

    const int tid = threadIdx.x, lane = tid & 63, wv = tid >> 6;
    const int wr = wv >> 2, wc = wv & 3;
    const int l15 = lane & 15, g = lane >> 4;

    f32x4 zero4 = {0.f, 0.f, 0.f, 0.f};
    f32x4 acc[8][4];
#pragma unroll
    for (int i = 0; i < 8; ++i)
#pragma unroll
        for (int j = 0; j < 4; ++j) acc[i][j] = zero4;

    const unsigned short* Ab = A + (size_t)mt * 256 * K;
    const unsigned short* Bb = Bt + (size_t)nt * 256 * K;

    // staging: 2048 16B-chunks per operand tile; 4 per thread. LDS dest linear,
    // source column inverse-swizzled (involution within each 8-chunk row).
    const unsigned short* As[4];
    const unsigned short* Bs[4];
    int ldst[4];
#pragma unroll
    for (int j = 0; j < 4; ++j) {
        int ch = tid + j * 512;
        int row = ch >> 3, cpos = ch & 7;
        int scol = ((cpos ^ (row & 7)) << 3);
        As[j] = Ab + (size_t)row * K + scol;
        Bs[j] = Bb + (size_t)row * K + scol;
        ldst[j] = ch * 8;
    }

#define STG(bufi_, k0_) {                                                         \
    _Pragma("unroll")                                                             \
    for (int j = 0; j < 4; ++j)                                                   \
        __builtin_amdgcn_global_load_lds(as_gbl(As[j] + (k0_)),                   \
                                         as_lds(&Al[bufi_][ldst[j]]), 16, 0, 0);  \
    _Pragma("unroll")                                                             \
    for (int j = 0; j < 4; ++j)                                                   \
        __builtin_amdgcn_global_load_lds(as_gbl(Bs[j] + (k0_)),                   \
                                         as_lds(&Bl[bufi_][ldst[j]]), 16, 0, 0); }

    STG(0, 0);
    __syncthreads();

    for (int t = 0; t < 8; ++t) {
        const int cur = t & 1;
        if (t < 7) STG(cur ^ 1, (t + 1) * 64);
        const unsigned short* Ar = Al[cur];
        const unsigned short* Br = Bl[cur];
#pragma unroll
        for (int s = 0; s < 2; ++s) {
            bf16x8 bf[4], af[8];
#pragma unroll
            for (int n = 0; n < 4; ++n)
                bf[n] = ldsrd64(Br, wc * 64 + n * 16 + l15, s * 4 + g);
#pragma unroll
            for (int m = 0; m < 8; ++m)
                af[m] = ldsrd64(Ar, wr * 128 + m * 16 + l15, s * 4 + g);
            __builtin_amdgcn_s_setprio(1);
#pragma unroll
            for (int m = 0; m < 8; ++m)
#pragma unroll
                for (int n = 0; n < 4; ++n)
                    acc[m][n] = __builtin_amdgcn_mfma_f32_16x16x32_bf16(af[m], bf[n], acc[m][n], 0, 0, 0);
            __builtin_amdgcn_s_setprio(0);
        }
        __syncthreads();   // drains vmcnt(0)+lgkmcnt(0): next-tile stage landed, reads done
    }
#undef STG

    const int mrow = mt * 256 + wr * 128;
    const int ncol = nt * 256 + wc * 64;
#pragma unroll
    for (int i = 0; i < 8; ++i) {
        int rowb = mrow + i * 16 + g * 4;
#pragma unroll
        for (int j = 0; j < 4; ++j) {
            int col = ncol + j * 16 + l15;
            float bv = bias[col];
#pragma unroll
            for (int rr = 0; rr < 4; ++rr)
                Cout[(size_t)(rowb + rr) * N + col] = acc[i][j][rr] + bv;
        }
    }
}

extern "C" void kernel_launch(void* const* d_in, const int* in_sizes, int n_in,
                              void* d_out, int out_size, void* d_ws, size_t ws_size,
                              hipStream_t stream)
{
    const int*           ids = (const int*)d_in[0];
    const unsigned char* pad = (const unsigned char*)d_in[1];
    const float*         tbl = (const float*)d_in[2];
    const float*         sfs = (const float*)d_in[3];
    const float*         als = (const float*)d_in[4];
    const float*         fw  = (const float*)d_in[5];
    const float*         fb  = (const float*)d_in[6];
    const float*         ow  = (const float*)d_in[7];
    const float*         ob  = (const float*)d_in[8];
    float* logits = (float*)d_out;

    // d_ws layout (60 MB)
    char* ws = (char*)d_ws;
    unsigned short* outw_bf = (unsigned short*)(ws);              // 32,768,000 B
    unsigned short* fusw_bf = (unsigned short*)(ws + 32768000);   //  2,097,152 B
    unsigned short* emb_bf  = (unsigned short*)(ws + 34865152);   //  4,194,304 B
    unsigned short* concat  = (unsigned short*)(ws + 39059456);   // 16,777,216 B
    unsigned short* fused   = (unsigned short*)(ws + 55836672);   //  4,194,304 B

    // scratch inside d_out (dead until final GEMM overwrites it)
    char* ob_scratch = (char*)d_out;
    unsigned short* P    = (unsigned short*)(ob_scratch);              // 67,108,864 B
    unsigned short* embT = (unsigned short*)(ob_scratch + 67108864);   //  4,194,304 B
    float*          dtab = (float*)(ob_scratch + 71303168);            //     32,768 B
    float*          lsum = (float*)(ob_scratch + 71335936);            //     65,536 B

    k_prep<<<6960, 256, 0, stream>>>(ids, tbl, als, fw, ow,
                                     outw_bf, fusw_bf, emb_bf, embT, dtab, lsum);

    dim3 bg(32, 32, BB);
    k_base<<<bg, 256, 0, stream>>>(emb_bf, pad, sfs, dtab, P, lsum);

    dim3 pg(64, BB, HH);
    k_pv<<<pg, 256, 0, stream>>>(P, embT, lsum, concat);

    k_gemm_bt<0><<<32 * 4, 256, 0, stream>>>(concat, fusw_bf, fb, fused, BB * SB, DD, HH * DD);
    k_logits<<<16 * 125, 512, 0, stream>>>(fused, outw_bf, ob, logits, BB * SB, VV, DD);
}

// Round 7
// 373.096 us; speedup vs baseline: 2.0843x; 1.0175x over previous
//
#include <hip/hip_runtime.h>
#include <hip/hip_bf16.h>
#include <stdint.h>

#define BB 2
#define SB 2048
#define DD 512
#define HH 4
#define VV 32000

typedef __attribute__((ext_vector_type(4))) float f32x4;
typedef __attribute__((ext_vector_type(8))) short bf16x8;
typedef __attribute__((ext_vector_type(4))) unsigned short us4;

__device__ __forceinline__ unsigned short f2bf(float f) {
    unsigned u = __float_as_uint(f);
    u += 0x7fffu + ((u >> 16) & 1u);
    return (unsigned short)(u >> 16);
}

__device__ __forceinline__ __attribute__((address_space(3))) unsigned int*
as_lds(void* p) {
    return (__attribute__((address_space(3))) unsigned int*)(unsigned)(uintptr_t)p;
}
__device__ __forceinline__ const __attribute__((address_space(1))) unsigned int*
as_gbl(const void* p) {
    return (const __attribute__((address_space(1))) unsigned int*)(uintptr_t)p;
}

// swizzled read from a [rows][64] bf16 LDS tile (128B rows): logical 16B-chunk c
// lives at slot c^(row&7). 16 lanes (same c, rows r..r+15) hit 8 slots x2 = 2-way free.
__device__ __forceinline__ bf16x8 ldsrd64(const unsigned short* base, int row, int c) {
    return *(const bf16x8*)((const char*)base + row * 128 + ((c ^ (row & 7)) << 4));
}

// ---------------- merged prep kernel ----------------
__global__ void k_prep(const int* __restrict__ ids, const float* __restrict__ tbl,
                       const float* __restrict__ als,
                       const float* __restrict__ fw, const float* __restrict__ ow,
                       unsigned short* __restrict__ outw_bf, unsigned short* __restrict__ fusw_bf,
                       unsigned short* __restrict__ emb, unsigned short* __restrict__ embT,
                       float* __restrict__ dtab, float* __restrict__ lsum)
{
    __shared__ unsigned short TT[64][72];
    const int bid = blockIdx.x, t = threadIdx.x;

    if (bid < 2000) {
        int base = bid * 8192 + t * 4;
#pragma unroll
        for (int it = 0; it < 8; ++it) {
            int i = base + it * 1024;
            float4 v = *(const float4*)(ow + i);
            us4 o; o.x = f2bf(v.x); o.y = f2bf(v.y); o.z = f2bf(v.z); o.w = f2bf(v.w);
            *(us4*)(outw_bf + i) = o;
        }
    } else if (bid < 2256) {
        int base = (bid - 2000) * 4096 + t * 4;
#pragma unroll
        for (int it = 0; it < 4; ++it) {
            int i = base + it * 1024;
            float4 v = *(const float4*)(fw + i);
            us4 o; o.x = f2bf(v.x); o.y = f2bf(v.y); o.z = f2bf(v.z); o.w = f2bf(v.w);
            *(us4*)(fusw_bf + i) = o;
        }
    } else if (bid < 6352) {
        int row = bid - 2256;
        int id = ids[row];
        if (id < 0) id = 0;
        if (id >= VV) id = VV - 1;
        const float* s = tbl + (size_t)id * DD;
        unsigned short* d = emb + (size_t)row * DD;
        d[t]       = f2bf(s[t]);
        d[t + 256] = f2bf(s[t + 256]);
    } else if (bid < 6448) {
        int i = (bid - 6352) * 256 + t;
        if (i < HH * SB) {
            int h = i >> 11, dd = i & (SB - 1);
            dtab[i] = 0.04419417382415922f / (1.f + als[h] * (float)dd);
        } else {
            lsum[i - HH * SB] = 0.f;
        }
    } else {
        int bid2 = bid - 6448;
        const int d0 = (bid2 & 7) * 64, s0 = ((bid2 >> 3) & 31) * 64, b = bid2 >> 8;
        {
            int s = t >> 2, c16 = (t & 3) * 16;
            int id = ids[b * SB + s0 + s];
            if (id < 0) id = 0;
            if (id >= VV) id = VV - 1;
            const float* src = tbl + (size_t)id * DD + d0 + c16;
#pragma unroll
            for (int q4 = 0; q4 < 4; ++q4) {
                float4 v = *(const float4*)(src + q4 * 4);
                TT[c16 + q4 * 4 + 0][s] = f2bf(v.x);
                TT[c16 + q4 * 4 + 1][s] = f2bf(v.y);
                TT[c16 + q4 * 4 + 2][s] = f2bf(v.z);
                TT[c16 + q4 * 4 + 3][s] = f2bf(v.w);
            }
        }
        __syncthreads();
        {
            int d = t >> 2, sc = (t & 3) * 16;
            bf16x8 o0, o1;
#pragma unroll
            for (int j = 0; j < 8; ++j) {
                o0[j] = (short)TT[d][sc + j];
                o1[j] = (short)TT[d][sc + 8 + j];
            }
            unsigned short* dst = embT + ((size_t)(b * DD + d0 + d)) * SB + s0 + sc;
            *(bf16x8*)dst = o0;
            *(bf16x8*)(dst + 8) = o1;
        }
    }
}

// ---------------- phase 2: shared base QK^T -> per-head P tiles + row sums ----------------
__launch_bounds__(256, 2)
__global__ void k_base(const unsigned short* __restrict__ emb,
                       const unsigned char* __restrict__ pad,
                       const float* __restrict__ sfs,
                       const float* __restrict__ dtab,
                       unsigned short* __restrict__ P,      // [4][2][2048][2048]
                       float* __restrict__ lsum)            // [4][2][2048]
{
    const int kt = blockIdx.x, qt = blockIdx.y, b = blockIdx.z;
    if (kt > qt + 1) return;
    const int tid = threadIdx.x, lane = tid & 63, wv = tid >> 6;
    const int l15 = lane & 15, g = lane >> 4;

    if (kt == qt + 1) {
        int row = tid >> 2, cb = (tid & 3) * 16;
        int4 z = {0, 0, 0, 0};
#pragma unroll
        for (int h = 0; h < 4; ++h) {
            unsigned short* Ph = P + (((size_t)(h * 2 + b)) * SB + qt * 64 + row) * SB + kt * 64 + cb;
            *(int4*)Ph = z;
            *(int4*)(Ph + 8) = z;
        }
        return;
    }

    __shared__ __align__(16) unsigned short Ql[64 * 128];
    __shared__ __align__(16) unsigned short Kl[64 * 128];

    const int q = qt * 64 + wv * 16 + l15;

    f32x4 zero4 = {0.f, 0.f, 0.f, 0.f};
    f32x4 cc[4];
#pragma unroll
    for (int c = 0; c < 4; ++c) cc[c] = zero4;

    for (int dc = 0; dc < 4; ++dc) {
        const int d0 = dc * 128;
        __syncthreads();
#pragma unroll
        for (int i = 0; i < 4; ++i) {
            int flat = (i * 256 + tid) * 8;
            int row = flat >> 7;
            int ch  = (flat >> 3) & 15;
            int scol = ((ch ^ (row & 15)) << 3);
            __builtin_amdgcn_global_load_lds(
                as_gbl(emb + ((size_t)(b * SB + qt * 64 + row)) * DD + d0 + scol),
                as_lds(Ql + flat), 16, 0, 0);
            __builtin_amdgcn_global_load_lds(
                as_gbl(emb + ((size_t)(b * SB + kt * 64 + row)) * DD + d0 + scol),
                as_lds(Kl + flat), 16, 0, 0);
        }
        asm volatile("s_waitcnt vmcnt(0)" ::: "memory");
        __syncthreads();

#pragma unroll
        for (int dsl = 0; dsl < 4; ++dsl) {
            int chr = (dsl * 4 + g);
            bf16x8 qf = *(const bf16x8*)(Ql + (wv * 16 + l15) * 128 + ((chr ^ l15) << 3));
#pragma unroll
            for (int c = 0; c < 4; ++c) {
                bf16x8 kf = *(const bf16x8*)(Kl + (c * 16 + l15) * 128 + ((chr ^ l15) << 3));
                cc[c] = __builtin_amdgcn_mfma_f32_16x16x32_bf16(kf, qf, cc[c], 0, 0, 0);
            }
        }
    }

    unsigned long long padm = __ballot(pad[(size_t)b * SB + kt * 64 + lane] != 0);

    const int wins[4] = {1 << 30, 128, 512, 1 << 30};
#pragma unroll
    for (int h = 0; h < 4; ++h) {
        const int win = wins[h];
        if (kt * 64 + win + 192 < qt * 64) continue;
        const float sf = sfs[h];
        const float* dth = dtab + h * SB;
        float rsum = 0.f;
        unsigned short pb[4][4];
#pragma unroll
        for (int c = 0; c < 4; ++c) {
#pragma unroll
            for (int r = 0; r < 4; ++r) {
                int kk = kt * 64 + c * 16 + 4 * g + r;
                int dist = q - kk;
                float p = 0.f;
                if (dist >= 0 && dist <= win &&
                    ((dist == 0) || !((padm >> (c * 16 + 4 * g + r)) & 1ull))) {
                    float s = cc[c][r] * dth[dist];
                    if (dist == 0) s *= sf;
                    p = __expf(s);
                }
                rsum += p;
                pb[c][r] = f2bf(p);
            }
        }
        unsigned short* Ph = P + (((size_t)(h * 2 + b)) * SB + q) * SB + kt * 64;
#pragma unroll
        for (int c = 0; c < 4; ++c) {
            us4 o;
            o.x = pb[c][0]; o.y = pb[c][1]; o.z = pb[c][2]; o.w = pb[c][3];
            *(us4*)(Ph + c * 16 + 4 * g) = o;
        }
        rsum += __shfl_xor(rsum, 16, 64);
        rsum += __shfl_xor(rsum, 32, 64);
        if (lane < 16)
            atomicAdd(&lsum[((size_t)(h * 2 + b)) * SB + q], rsum);
    }
}

// ---------------- phase 3: ctx = P * V^T, normalize, write concat ----------------
__launch_bounds__(256, 2)
__global__ void k_pv(const unsigned short* __restrict__ P,
                     const unsigned short* __restrict__ embT,
                     const float* __restrict__ lsum,
                     unsigned short* __restrict__ concat)
{
    const int t64 = blockIdx.x, b = blockIdx.y, h = blockIdx.z;
    const int mt = t64 >> 2, nt = t64 & 3;
    const int Q0 = mt * 128;
    const int win = (h == 1) ? 128 : (h == 2) ? 512 : (1 << 30);
    int klo = Q0 - win - 64; if (klo < 0) klo = 0; klo &= ~63;
    const int khi = Q0 + 128;

    __shared__ __align__(16) unsigned short Al[128 * 32];
    __shared__ __align__(16) unsigned short Bl[128 * 32];

    const int tid = threadIdx.x, lane = tid & 63, wv = tid >> 6;
    const int wm = (wv >> 1) * 64, wn = (wv & 1) * 64;
    const int l15 = lane & 15, g = lane >> 4;

    f32x4 zero4 = {0.f, 0.f, 0.f, 0.f};
    f32x4 acc[4][4];
#pragma unroll
    for (int i = 0; i < 4; ++i)
#pragma unroll
        for (int j = 0; j < 4; ++j) acc[i][j] = zero4;

    const unsigned short* Ab = P + (((size_t)(h * 2 + b)) * SB + Q0) * SB;
    const unsigned short* Bb = embT + ((size_t)(b * DD + nt * 128)) * SB;

    for (int k0 = klo; k0 < khi; k0 += 32) {
        __syncthreads();
#pragma unroll
        for (int s = 0; s < 2; ++s) {
            int e = (s * 256 + tid) * 8;
            int row = e >> 5, col = e & 31;
            __builtin_amdgcn_global_load_lds(as_gbl(Ab + (size_t)row * SB + k0 + col),
                                             as_lds(Al + e), 16, 0, 0);
            __builtin_amdgcn_global_load_lds(as_gbl(Bb + (size_t)row * SB + k0 + col),
                                             as_lds(Bl + e), 16, 0, 0);
        }
        asm volatile("s_waitcnt vmcnt(0)" ::: "memory");
        __syncthreads();

        bf16x8 af[4], bfr[4];
#pragma unroll
        for (int i = 0; i < 4; ++i) {
            af[i]  = *(const bf16x8*)(Al + (wm + i * 16 + l15) * 32 + 8 * g);
            bfr[i] = *(const bf16x8*)(Bl + (wn + i * 16 + l15) * 32 + 8 * g);
        }
#pragma unroll
        for (int i = 0; i < 4; ++i)
#pragma unroll
            for (int j = 0; j < 4; ++j)
                acc[i][j] = __builtin_amdgcn_mfma_f32_16x16x32_bf16(af[i], bfr[j], acc[i][j], 0, 0, 0);
    }

    const float* ls = lsum + ((size_t)(h * 2 + b)) * SB;
    unsigned short* cb = concat + ((size_t)(b * SB)) * (HH * DD) + h * DD + nt * 128;
#pragma unroll
    for (int i = 0; i < 4; ++i) {
        int rowb = wm + i * 16 + g * 4;
        float inv[4];
#pragma unroll
        for (int rr = 0; rr < 4; ++rr) inv[rr] = 1.f / ls[Q0 + rowb + rr];
#pragma unroll
        for (int j = 0; j < 4; ++j) {
            int col = wn + j * 16 + l15;
#pragma unroll
            for (int rr = 0; rr < 4; ++rr)
                cb[(size_t)(Q0 + rowb + rr) * (HH * DD) + col] = f2bf(acc[i][j][rr] * inv[rr]);
        }
    }
}

// ---------------- m97-style 128x128 GEMM (fusion GEMM) ----------------
template <int OUTF32>
__launch_bounds__(256, 2)
__global__ void k_gemm_bt(const unsigned short* __restrict__ A,
                          const unsigned short* __restrict__ Bt,
                          const float* __restrict__ bias,
                          void* __restrict__ Cout,
                          int M, int N, int K)
{
    const int nMt = M >> 7;
    const int nwg = gridDim.x;
    int bid = blockIdx.x;
    int q = nwg >> 3, r = nwg & 7;
    int x = bid & 7, o = bid >> 3;
    int wg = (x < r ? x * (q + 1) : r * (q + 1) + (x - r) * q) + o;
    const int mt = wg % nMt, nt = wg / nMt;

    __shared__ __align__(16) unsigned short Al[128 * 32];
    __shared__ __align__(16) unsigned short Bl[128 * 32];

    const int tid = threadIdx.x;
    const int lane = tid & 63;
    const int wv = tid >> 6;
    const int wm = (wv >> 1) * 64, wn = (wv & 1) * 64;
    const int l15 = lane & 15, g = lane >> 4;

    f32x4 zero4 = {0.f, 0.f, 0.f, 0.f};
    f32x4 acc[4][4];
#pragma unroll
    for (int i = 0; i < 4; ++i)
#pragma unroll
        for (int j = 0; j < 4; ++j) acc[i][j] = zero4;

    const unsigned short* Ab = A + (size_t)mt * 128 * K;
    const unsigned short* Bb = Bt + (size_t)nt * 128 * K;

    for (int k0 = 0; k0 < K; k0 += 32) {
        __syncthreads();
#pragma unroll
        for (int s = 0; s < 2; ++s) {
            int e = (s * 256 + tid) * 8;
            int row = e >> 5, col = e & 31;
            __builtin_amdgcn_global_load_lds(as_gbl(Ab + (size_t)row * K + k0 + col),
                                             as_lds(Al + e), 16, 0, 0);
            __builtin_amdgcn_global_load_lds(as_gbl(Bb + (size_t)row * K + k0 + col),
                                             as_lds(Bl + e), 16, 0, 0);
        }
        asm volatile("s_waitcnt vmcnt(0)" ::: "memory");
        __syncthreads();

        bf16x8 af[4], bfr[4];
#pragma unroll
        for (int i = 0; i < 4; ++i) {
            af[i]  = *(const bf16x8*)(Al + (wm + i * 16 + l15) * 32 + 8 * g);
            bfr[i] = *(const bf16x8*)(Bl + (wn + i * 16 + l15) * 32 + 8 * g);
        }
#pragma unroll
        for (int i = 0; i < 4; ++i)
#pragma unroll
            for (int j = 0; j < 4; ++j)
                acc[i][j] = __builtin_amdgcn_mfma_f32_16x16x32_bf16(af[i], bfr[j], acc[i][j], 0, 0, 0);
    }

#pragma unroll
    for (int i = 0; i < 4; ++i) {
        int rowb = mt * 128 + wm + i * 16 + g * 4;
#pragma unroll
        for (int j = 0; j < 4; ++j) {
            int col = nt * 128 + wn + j * 16 + l15;
            float bv = bias[col];
            if (OUTF32) {
                float* C = (float*)Cout;
#pragma unroll
                for (int rr = 0; rr < 4; ++rr)
                    C[(size_t)(rowb + rr) * N + col] = acc[i][j][rr] + bv;
            } else {
                unsigned short* C = (unsigned short*)Cout;
#pragma unroll
                for (int rr = 0; rr < 4; ++rr)
                    C[(size_t)(rowb + rr) * N + col] = f2bf(acc[i][j][rr] + bv);
            }
        }
    }
}

// ---------------- logits GEMM: 256x256 tile, BK=64, double-buffer ----------------
// Identical to R5 except the epilogue: LDS-staged, full-line coalesced stores.
__launch_bounds__(512, 1)
__global__ void k_logits(const unsigned short* __restrict__ A,
                         const unsigned short* __restrict__ Bt,
                         const float* __restrict__ bias,
                         float* __restrict__ Cout,
                         int M, int N, int K)
{
    const int nMt = M >> 8;
    const int nwg = gridDim.x;
    int bid = blockIdx.x;
    int q = nwg >> 3, r = nwg & 7;
    int x = bid & 7, o = bid >> 3;
    int wg = (x < r ? x * (q + 1) : r * (q + 1) + (x - r) * q) + o;
    const int mt = wg % nMt, nt = wg / nMt;

    __shared__ __align__(16) char smem[131072];

    const int tid = threadIdx.x, lane = tid & 63, wv = tid >> 6;
    const int wr = wv >> 2, wc = wv & 3;
    const int l15 = lane & 15, g = lane >> 4;

    f32x4 zero4 = {0.f, 0.f, 0.f, 0.f};
    f32x4 acc[8][4];
#pragma unroll
    for (int i = 0; i < 8; ++i)
#pragma unroll
        for (int j = 0; j < 4; ++j) acc[i][j] = zero4;

    const unsigned short* Ab = A + (size_t)mt * 256 * K;
    const unsigned short* Bb = Bt + (size_t)nt * 256 * K;

    const unsigned short* As[4];
    const unsigned short* Bs[4];
    int ldstA[4], ldstB[4];
#pragma unroll
    for (int j = 0; j < 4; ++j) {
        int ch = tid + j * 512;
        int row = ch >> 3, cpos = ch & 7;
        int scol = ((cpos ^ (row & 7)) << 3);
        As[j] = Ab + (size_t)row * K + scol;
        Bs[j] = Bb + (size_t)row * K + scol;
        ldstA[j] = ch * 16;                  // byte offset within A half
        ldstB[j] = 65536 + ch * 16;          // byte offset within B half
    }

#define STG(bufi_, k0_) {                                                              \
    _Pragma("unroll")                                                                  \
    for (int j = 0; j < 4; ++j)                                                        \
        __builtin_amdgcn_global_load_lds(as_gbl(As[j] + (k0_)),                        \
            as_lds(smem + (bufi_) * 32768 + ldstA[j]), 16, 0, 0);                      \
    _Pragma("unroll")                                                                  \
    for (int j = 0; j < 4; ++j)                                                        \
        __builtin_amdgcn_global_load_lds(as_gbl(Bs[j] + (k0_)),                        \
            as_lds(smem + (bufi_) * 32768 + ldstB[j]), 16, 0, 0); }

    STG(0, 0);
    __syncthreads();

    for (int t = 0; t < 8; ++t) {
        const int cur = t & 1;
        if (t < 7) STG(cur ^ 1, (t + 1) * 64);
        const unsigned short* Ar = (const unsigned short*)(smem + cur * 32768);
        const unsigned short* Br = (const unsigned short*)(smem + cur * 32768 + 65536);
#pragma unroll
        for (int s = 0; s < 2; ++s) {
            bf16x8 bf[4], af[8];
#pragma unroll
            for (int n = 0; n < 4; ++n)
                bf[n] = ldsrd64(Br, wc * 64 + n * 16 + l15, s * 4 + g);
#pragma unroll
            for (int m = 0; m < 8; ++m)
                af[m] = ldsrd64(Ar, wr * 128 + m * 16 + l15, s * 4 + g);
            __builtin_amdgcn_s_setprio(1);
#pragma unroll
            for (int m = 0; m < 8; ++m)
#pragma unroll
                for (int n = 0; n < 4; ++n)
                    acc[m][n] = __builtin_amdgcn_mfma_f32_16x16x32_bf16(af[m], bf[n], acc[m][n], 0, 0, 0);
            __builtin_amdgcn_s_setprio(0);
        }
        __syncthreads();
    }
#undef STG

    // ---- epilogue: LDS-staged, full-line coalesced f32 stores ----
    // 8 chunks of 32 rows; Cl stride 258 f32 (bank-spread, <=2-way).
    const int mrow = mt * 256;
    const int ncol = nt * 256;
    float* Cl = (float*)smem;
    float bvj[4];
#pragma unroll
    for (int j = 0; j < 4; ++j) bvj[j] = bias[ncol + wc * 64 + j * 16 + l15];
    const int srow = tid >> 4;            // 0..31
    const int scol = (tid & 15) * 4;      // 0..60 step 4
    const float* Crd = Cl + srow * 258 + scol;
#pragma unroll
    for (int mc = 0; mc < 8; ++mc) {
        if (wr == (mc >> 2)) {
            int ibase = (mc & 3) * 2;
#pragma unroll
            for (int ii = 0; ii < 2; ++ii) {
                int i = ibase + ii;
                int lr = ii * 16 + g * 4;
#pragma unroll
                for (int j = 0; j < 4; ++j)
#pragma unroll
                    for (int rr = 0; rr < 4; ++rr)
                        Cl[(lr + rr) * 258 + wc * 64 + j * 16 + l15] = acc[i][j][rr] + bvj[j];
            }
        }
        __syncthreads();
        {
            float* gp = Cout + (size_t)(mrow + mc * 32 + srow) * N + ncol + scol;
#pragma unroll
            for (int it = 0; it < 4; ++it)
                *(float4*)(gp + it * 64) = *(const float4*)(Crd + it * 64);
        }
        __syncthreads();
    }
}

extern "C" void kernel_launch(void* const* d_in, const int* in_sizes, int n_in,
                              void* d_out, int out_size, void* d_ws, size_t ws_size,
                              hipStream_t stream)
{
    const int*           ids = (const int*)d_in[0];
    const unsigned char* pad = (const unsigned char*)d_in[1];
    const float*         tbl = (const float*)d_in[2];
    const float*         sfs = (const float*)d_in[3];
    const float*         als = (const float*)d_in[4];
    const float*         fw  = (const float*)d_in[5];
    const float*         fb  = (const float*)d_in[6];
    const float*         ow  = (const float*)d_in[7];
    const float*         ob  = (const float*)d_in[8];
    float* logits = (float*)d_out;

    // d_ws layout (60 MB)
    char* ws = (char*)d_ws;
    unsigned short* outw_bf = (unsigned short*)(ws);              // 32,768,000 B
    unsigned short* fusw_bf = (unsigned short*)(ws + 32768000);   //  2,097,152 B
    unsigned short* emb_bf  = (unsigned short*)(ws + 34865152);   //  4,194,304 B
    unsigned short* concat  = (unsigned short*)(ws + 39059456);   // 16,777,216 B
    unsigned short* fused   = (unsigned short*)(ws + 55836672);   //  4,194,304 B

    // scratch inside d_out (dead until final GEMM overwrites it)
    char* ob_scratch = (char*)d_out;
    unsigned short* P    = (unsigned short*)(ob_scratch);              // 67,108,864 B
    unsigned short* embT = (unsigned short*)(ob_scratch + 67108864);   //  4,194,304 B
    float*          dtab = (float*)(ob_scratch + 71303168);            //     32,768 B
    float*          lsum = (float*)(ob_scratch + 71335936);            //     65,536 B

    k_prep<<<6960, 256, 0, stream>>>(ids, tbl, als, fw, ow,
                                     outw_bf, fusw_bf, emb_bf, embT, dtab, lsum);

    dim3 bg(32, 32, BB);
    k_base<<<bg, 256, 0, stream>>>(emb_bf, pad, sfs, dtab, P, lsum);

    dim3 pg(64, BB, HH);
    k_pv<<<pg, 256, 0, stream>>>(P, embT, lsum, concat);

    k_gemm_bt<0><<<32 * 4, 256, 0, stream>>>(concat, fusw_bf, fb, fused, BB * SB, DD, HH * DD);
    k_logits<<<16 * 125, 512, 0, stream>>>(fused, outw_bf, ob, logits, BB * SB, VV, DD);
}